// Round 1
// baseline (25630.203 us; speedup 1.0000x reference)
//
#include <hip/hip_runtime.h>
#include <math.h>

// ---------------------------------------------------------------------------
// VQ-VAE forward, fp32 direct kernels (correctness-first baseline).
// Workspace layout (floats), total ~117.5 MB:
//   A  = ws[0 .. 16777216)            67.1 MB   h1 (64,64,64,64), later tc1 out
//   B2 = ws[0 ..  8388608)  (alias A) 33.6 MB   h3, later Zq_nchw (first 4.2M)
//   B1 = ws[16777216 .. +8388608)     33.6 MB   h2/h4/res trunk, later dec trunk
//   E1 = ws[25165824 .. +4194304)     16.8 MB   res mid / Ze
//   misc = ws[29360128 ..]            counts[512], sse[1]
// ---------------------------------------------------------------------------

#define WS_A   0
#define WS_B2  0
#define WS_B1  16777216
#define WS_E1  25165824
#define WS_MISC 29360128

// ---------------- generic direct conv ----------------
template<int CIN, int COUT, int KS, int STRIDE, int PAD,
         bool RELU_IN, bool RELU_OUT, bool ACC, bool HAS_BIAS>
__global__ void conv2d_k(const float* __restrict__ in,
                         const float* __restrict__ wgt,
                         const float* __restrict__ bias,
                         float* __restrict__ out,
                         int N, int Hin, int Win, int Hout, int Wout)
{
    int tid = blockIdx.x * blockDim.x + threadIdx.x;
    int total = N * COUT * Hout * Wout;
    if (tid >= total) return;
    int ow = tid % Wout;
    int t  = tid / Wout;
    int oh = t % Hout; t /= Hout;
    int co = t % COUT;
    int n  = t / COUT;

    const float* wb = wgt + co * (CIN * KS * KS);
    const float* ib = in + (size_t)n * CIN * Hin * Win;
    int ih0 = oh * STRIDE - PAD;
    int iw0 = ow * STRIDE - PAD;

    float acc = 0.0f;
    #pragma unroll 4
    for (int ci = 0; ci < CIN; ++ci) {
        const float* ic = ib + ci * (Hin * Win);
        const float* wc = wb + ci * (KS * KS);
        #pragma unroll
        for (int kh = 0; kh < KS; ++kh) {
            int ih = ih0 + kh;
            if ((unsigned)ih >= (unsigned)Hin) continue;
            #pragma unroll
            for (int kw = 0; kw < KS; ++kw) {
                int iw = iw0 + kw;
                if ((unsigned)iw >= (unsigned)Win) continue;
                float v = ic[ih * Win + iw];
                if (RELU_IN) v = fmaxf(v, 0.0f);
                acc = fmaf(v, wc[kh * KS + kw], acc);
            }
        }
    }
    if (HAS_BIAS) acc += bias[co];
    if (ACC) acc += out[tid];
    if (RELU_OUT) acc = fmaxf(acc, 0.0f);
    out[tid] = acc;
}

// ---------------- transposed conv, k=4 s=2 p=1 ----------------
// torch ConvTranspose2d weight layout: (Cin, Cout, kh, kw)
// out[oh] gets input[ih] at taps with oh = 2*ih - 1 + kh  (kh in [0,4))
template<int CIN, int COUT, bool RELU_IN, bool RELU_OUT>
__global__ void convt4s2p1_k(const float* __restrict__ in,
                             const float* __restrict__ wgt,
                             const float* __restrict__ bias,
                             float* __restrict__ out,
                             int N, int Hin, int Win)
{
    int Hout = Hin * 2, Wout = Win * 2;
    int tid = blockIdx.x * blockDim.x + threadIdx.x;
    int total = N * COUT * Hout * Wout;
    if (tid >= total) return;
    int ow = tid % Wout;
    int t  = tid / Wout;
    int oh = t % Hout; t /= Hout;
    int co = t % COUT;
    int n  = t / COUT;

    int khs[2], ihs[2], nkh = 0;
    #pragma unroll
    for (int kh = 0; kh < 4; ++kh) {
        int tt = oh + 1 - kh;
        if (tt >= 0 && (tt & 1) == 0 && (tt >> 1) < Hin) {
            khs[nkh] = kh; ihs[nkh] = tt >> 1; ++nkh;
        }
    }
    int kws[2], iws[2], nkw = 0;
    #pragma unroll
    for (int kw = 0; kw < 4; ++kw) {
        int tt = ow + 1 - kw;
        if (tt >= 0 && (tt & 1) == 0 && (tt >> 1) < Win) {
            kws[nkw] = kw; iws[nkw] = tt >> 1; ++nkw;
        }
    }

    float acc = 0.0f;
    const float* ib = in + (size_t)n * CIN * Hin * Win;
    #pragma unroll 4
    for (int ci = 0; ci < CIN; ++ci) {
        const float* ic = ib + ci * (Hin * Win);
        const float* wc = wgt + (ci * COUT + co) * 16;
        for (int a = 0; a < nkh; ++a) {
            for (int b = 0; b < nkw; ++b) {
                float v = ic[ihs[a] * Win + iws[b]];
                if (RELU_IN) v = fmaxf(v, 0.0f);
                acc = fmaf(v, wc[khs[a] * 4 + kws[b]], acc);
            }
        }
    }
    acc += bias[co];
    if (RELU_OUT) acc = fmaxf(acc, 0.0f);
    out[tid] = acc;
}

// ---------------- vector quantizer ----------------
// Ze: (64, 64, 32, 32) NCHW.  Position p = b*1024 + h*32 + w  (matches the
// reference's (B,H,W) flattening order).  D=64, K=512.
#define VQ_D 64
#define VQ_K 512
#define VQ_CHUNK 128

__global__ void vq_k(const float* __restrict__ Ze,
                     const float* __restrict__ E,
                     float* __restrict__ Zq,
                     float* __restrict__ counts,
                     float* __restrict__ sse)
{
    __shared__ float eld[VQ_CHUNK * VQ_D];
    __shared__ float enorm[VQ_CHUNK];
    __shared__ float red[256];

    int p = blockIdx.x * 256 + threadIdx.x;
    int b = p >> 10, rem = p & 1023, h = rem >> 5, w = rem & 31;
    int base = ((b * VQ_D) * 32 + h) * 32 + w;   // channel stride = 1024

    float z[VQ_D];
    #pragma unroll
    for (int d = 0; d < VQ_D; ++d) z[d] = Ze[base + d * 1024];

    float best = INFINITY;
    int bestk = 0;
    for (int k0 = 0; k0 < VQ_K; k0 += VQ_CHUNK) {
        __syncthreads();
        for (int i = threadIdx.x; i < VQ_CHUNK * VQ_D; i += 256)
            eld[i] = E[k0 * VQ_D + i];
        __syncthreads();
        if (threadIdx.x < VQ_CHUNK) {
            float s = 0.0f;
            #pragma unroll
            for (int d = 0; d < VQ_D; ++d) {
                float e = eld[threadIdx.x * VQ_D + d];
                s = fmaf(e, e, s);
            }
            enorm[threadIdx.x] = s;
        }
        __syncthreads();
        for (int k = 0; k < VQ_CHUNK; ++k) {
            float dot = 0.0f;
            #pragma unroll
            for (int d = 0; d < VQ_D; ++d)
                dot = fmaf(z[d], eld[k * VQ_D + d], dot);
            float score = enorm[k] - 2.0f * dot;
            if (score < best) { best = score; bestk = k0 + k; }  // first-min tie-break
        }
    }

    // quantized output + per-thread SSE
    float local = 0.0f;
    const float* eb = E + bestk * VQ_D;
    #pragma unroll
    for (int d = 0; d < VQ_D; ++d) {
        float e = eb[d];
        Zq[base + d * 1024] = e;
        float df = e - z[d];
        local = fmaf(df, df, local);
    }
    atomicAdd(&counts[bestk], 1.0f);

    red[threadIdx.x] = local;
    __syncthreads();
    for (int s = 128; s > 0; s >>= 1) {
        if (threadIdx.x < (unsigned)s) red[threadIdx.x] += red[threadIdx.x + s];
        __syncthreads();
    }
    if (threadIdx.x == 0) atomicAdd(sse, red[0]);
}

// ---------------- scalar outputs ----------------
__global__ void finalize_k(const float* __restrict__ counts,
                           const float* __restrict__ sse,
                           float* __restrict__ out_head,
                           float* __restrict__ out_tail)
{
    __shared__ float red[512];
    int t = threadIdx.x;
    float c = counts[t];
    float pr = c / 65536.0f;
    red[t] = -pr * log2f(pr + 1e-10f);
    __syncthreads();
    for (int s = 256; s > 0; s >>= 1) {
        if (t < s) red[t] += red[t + s];
        __syncthreads();
    }
    if (t == 0) {
        float entropy = red[0];
        float mse = sse[0] / 4194304.0f;     // N*D = 65536*64
        out_head[0] = 1.25f * mse;           // q + 0.25*e, both == mse in fwd
        out_tail[0] = mse;                   // e_latent_loss
        out_tail[1] = mse;                   // q_latent_loss
        out_tail[2] = exp2f(entropy);        // est_words
    }
}

__global__ void zero_k(float* __restrict__ p, int n)
{
    int i = blockIdx.x * blockDim.x + threadIdx.x;
    if (i < n) p[i] = 0.0f;
}

// ---------------------------------------------------------------------------
extern "C" void kernel_launch(void* const* d_in, const int* in_sizes, int n_in,
                              void* d_out, int out_size, void* d_ws, size_t ws_size,
                              hipStream_t stream)
{
    const float* x         = (const float*)d_in[0];
    const float* enc_w1    = (const float*)d_in[1];
    const float* enc_b1    = (const float*)d_in[2];
    const float* enc_w2    = (const float*)d_in[3];
    const float* enc_b2    = (const float*)d_in[4];
    const float* enc_w3    = (const float*)d_in[5];
    const float* enc_b3    = (const float*)d_in[6];
    const float* enc_w4    = (const float*)d_in[7];
    const float* enc_b4    = (const float*)d_in[8];
    const float* enc_res_w1= (const float*)d_in[9];
    const float* enc_res_w2= (const float*)d_in[10];
    const float* enc_adj_w = (const float*)d_in[11];
    const float* enc_adj_b = (const float*)d_in[12];
    const float* Ecb       = (const float*)d_in[13];
    const float* dec_adj_w = (const float*)d_in[14];
    const float* dec_adj_b = (const float*)d_in[15];
    const float* dec_res_w1= (const float*)d_in[16];
    const float* dec_res_w2= (const float*)d_in[17];
    const float* tc1_w     = (const float*)d_in[18];
    const float* tc1_b     = (const float*)d_in[19];
    const float* tc2_w     = (const float*)d_in[20];
    const float* tc2_b     = (const float*)d_in[21];

    float* ws = (float*)d_ws;
    float* A   = ws + WS_A;
    float* B2  = ws + WS_B2;   // aliases A's first 8.4M floats
    float* B1  = ws + WS_B1;
    float* E1  = ws + WS_E1;
    float* counts = ws + WS_MISC;
    float* sse    = counts + 512;

    float* out   = (float*)d_out;
    float* xrec  = out + 1;
    float* tail  = out + 1 + 3145728;

    const int BLK = 256;

    // zero accumulators (ws is poisoned 0xAA before every timed launch)
    zero_k<<<3, BLK, 0, stream>>>(counts, 513);

    // ---- encoder ----
    // conv1: x(64,3,128,128) -> A(64,64,64,64)  k4 s2 p1, bias+relu
    conv2d_k<3,64,4,2,1,false,true,false,true>
        <<<16777216/BLK, BLK, 0, stream>>>(x, enc_w1, enc_b1, A, 64, 128, 128, 64, 64);
    // conv2: A -> B1(64,128,32,32)  k4 s2 p1, bias+relu
    conv2d_k<64,128,4,2,1,false,true,false,true>
        <<<8388608/BLK, BLK, 0, stream>>>(A, enc_w2, enc_b2, B1, 64, 64, 64, 32, 32);
    // conv3: B1 -> B2  k3 s1 p1, bias+relu
    conv2d_k<128,128,3,1,1,false,true,false,true>
        <<<8388608/BLK, BLK, 0, stream>>>(B1, enc_w3, enc_b3, B2, 64, 32, 32, 32, 32);
    // conv4: B2 -> B1  k3 s1 p1, bias, NO relu
    conv2d_k<128,128,3,1,1,false,false,false,true>
        <<<8388608/BLK, BLK, 0, stream>>>(B2, enc_w4, enc_b4, B1, 64, 32, 32, 32, 32);

    // enc res stack (2 blocks): B1 += conv1x1(relu(conv3x3(relu(B1))))
    for (int i = 0; i < 2; ++i) {
        conv2d_k<128,64,3,1,1,true,false,false,false>
            <<<4194304/BLK, BLK, 0, stream>>>(B1, enc_res_w1 + i*64*128*9, nullptr, E1,
                                              64, 32, 32, 32, 32);
        conv2d_k<64,128,1,1,0,true,false,true,false>
            <<<8388608/BLK, BLK, 0, stream>>>(E1, enc_res_w2 + i*128*64, nullptr, B1,
                                              64, 32, 32, 32, 32);
    }
    // enc_adj: relu(B1) -> Ze in E1   (1x1, 128->64, bias); final res-stack relu fused
    conv2d_k<128,64,1,1,0,true,false,false,true>
        <<<4194304/BLK, BLK, 0, stream>>>(B1, enc_adj_w, enc_adj_b, E1, 64, 32, 32, 32, 32);

    // ---- VQ ----  Ze(E1) -> Zq(B2) + counts + sse
    vq_k<<<65536/BLK, BLK, 0, stream>>>(E1, Ecb, B2, counts, sse);

    // ---- decoder ----
    // dec_adj: Zq(B2) -> B1  k3 s1 p1, 64->128, bias
    conv2d_k<64,128,3,1,1,false,false,false,true>
        <<<8388608/BLK, BLK, 0, stream>>>(B2, dec_adj_w, dec_adj_b, B1, 64, 32, 32, 32, 32);
    // dec res stack
    for (int i = 0; i < 2; ++i) {
        conv2d_k<128,64,3,1,1,true,false,false,false>
            <<<4194304/BLK, BLK, 0, stream>>>(B1, dec_res_w1 + i*64*128*9, nullptr, E1,
                                              64, 32, 32, 32, 32);
        conv2d_k<64,128,1,1,0,true,false,true,false>
            <<<8388608/BLK, BLK, 0, stream>>>(E1, dec_res_w2 + i*128*64, nullptr, B1,
                                              64, 32, 32, 32, 32);
    }
    // tc1: relu(B1) -> A(64,64,64,64), transpose-conv k4 s2 p1, bias, relu out
    convt4s2p1_k<128,64,true,true>
        <<<16777216/BLK, BLK, 0, stream>>>(B1, tc1_w, tc1_b, A, 64, 32, 32);
    // tc2: A -> x_recon(64,3,128,128), no relu
    convt4s2p1_k<64,3,false,false>
        <<<3145728/BLK, BLK, 0, stream>>>(A, tc2_w, tc2_b, xrec, 64, 64, 64);

    // ---- scalar outputs ----
    finalize_k<<<1, 512, 0, stream>>>(counts, sse, out, tail);
}

// Round 2
// 1569.669 us; speedup vs baseline: 16.3284x; 16.3284x over previous
//
#include <hip/hip_runtime.h>
#include <math.h>

// ---------------------------------------------------------------------------
// VQ-VAE forward: NHWC bf16 trunk, implicit-GEMM MFMA convs (fp32 accum).
//
// Workspace layout (bytes):
//   [0 .. ~1.95MB)   transformed weights (bf16 [tap][co][ci]) + wc1 fp32 + counts/sse
//   H1  = 2097152   (64,64,64,64)  NHWC bf16  33.5MB   h1, later tc1 out
//   TR  = 35651584  (64,32,32,128) NHWC bf16  16.8MB   enc trunk
//   H3  = 52428800  (64,32,32,128) NHWC bf16  16.8MB   h3, later dec trunk
//   MID = 69206016  (64,32,32,64)  NHWC bf16   8.4MB   res mid
//   ZE  = 77594624  (64,32,32,64)  NHWC bf16   8.4MB
//   ZQ  = 85983232  (64,32,32,64)  NHWC bf16   8.4MB
// ---------------------------------------------------------------------------

typedef unsigned short u16;
typedef __attribute__((ext_vector_type(8))) short bf16x8;
typedef __attribute__((ext_vector_type(4))) float f32x4;

__device__ __forceinline__ float bf2f(u16 h) {
    union { unsigned u; float f; } v; v.u = ((unsigned)h) << 16; return v.f;
}
__device__ __forceinline__ u16 f2bf(float f) {
    union { float f; unsigned u; } v; v.f = f;
    unsigned r = v.u + 0x7FFFu + ((v.u >> 16) & 1u);
    return (u16)(r >> 16);
}
// packed relu on 2 bf16 halves of a uint
__device__ __forceinline__ unsigned relu2(unsigned x) {
    return x & ~(((x & 0x80008000u) >> 15) * 0xFFFFu);
}

struct Taps { int s; int ntaps; int dh[16]; int dw[16]; };

// ---------------- unified implicit-GEMM MFMA conv ----------------
// in : NHWC bf16 (64, Hin, Win, CIN)
// wT : bf16 [tap][co][ci]
// out: NHWC bf16 (64, Hout, Wout, COUT), written at (oh*OS+OPH, ow*OS+OPW)
// M-grid is always 64 images x 32x32 positions; blockIdx.x covers M/128.
template<int CIN, int COUT, bool RELU_IN, bool RELU_OUT, bool HAS_BIAS, bool RESID>
__global__ __launch_bounds__(256)
void mfma_conv_k(const u16* __restrict__ in, const u16* __restrict__ wT,
                 const float* __restrict__ bias, u16* __restrict__ out,
                 int Hin, int Win, int Hout, int Wout, int OS, int OPH, int OPW,
                 Taps taps)
{
    constexpr int WN = (COUT == 128) ? 2 : 1;
    constexpr int WM = 4 / WN;
    constexpr int TM = (128 / WM) / 16;
    constexpr int TN = (COUT / WN) / 16;
    constexpr int LDA = 40;  // 32 data + 8 pad (keeps 16B align, breaks stride-32 aliasing)

    __shared__ alignas(16) u16 aT[128 * LDA];
    __shared__ alignas(16) u16 bT[COUT * LDA];

    const int tid = threadIdx.x;
    const int m0 = blockIdx.x * 128;
    const int n_img = m0 >> 10;
    const int pixbase = m0 & 1023;

    const int r = tid >> 1, half = tid & 1;        // staging: row r, 32B half
    const int pr = pixbase + r;
    const int ohr = pr >> 5, owr = pr & 31;
    const u16* inb = in + (size_t)n_img * Hin * Win * CIN;

    const int wv = tid >> 6, lane = tid & 63;
    const int q = lane >> 4, l16 = lane & 15;
    const int wm = wv / WN, wn = wv % WN;
    const int mbase = wm * (TM * 16), cbase = wn * (TN * 16);

    f32x4 acc[TM][TN] = {};

    for (int t = 0; t < taps.ntaps; ++t) {
        const int ih = ohr * taps.s + taps.dh[t];
        const int iw = owr * taps.s + taps.dw[t];
        const bool ok = ((unsigned)ih < (unsigned)Hin) && ((unsigned)iw < (unsigned)Win);
        const u16* asrc = ok ? (inb + ((size_t)ih * Win + iw) * CIN + half * 16) : inb;
        const u16* bsrc = wT + ((size_t)t * COUT + r) * CIN + half * 16;

        for (int c0 = 0; c0 < CIN; c0 += 32) {
            __syncthreads();
            uint4 a0 = {0,0,0,0}, a1 = {0,0,0,0};
            if (ok) {
                a0 = *(const uint4*)(asrc + c0);
                a1 = *(const uint4*)(asrc + c0 + 8);
            }
            if (RELU_IN) {
                a0.x = relu2(a0.x); a0.y = relu2(a0.y); a0.z = relu2(a0.z); a0.w = relu2(a0.w);
                a1.x = relu2(a1.x); a1.y = relu2(a1.y); a1.z = relu2(a1.z); a1.w = relu2(a1.w);
            }
            *(uint4*)&aT[r * LDA + half * 16]     = a0;
            *(uint4*)&aT[r * LDA + half * 16 + 8] = a1;
            if (COUT == 128 || r < COUT) {
                uint4 b0 = *(const uint4*)(bsrc + c0);
                uint4 b1 = *(const uint4*)(bsrc + c0 + 8);
                *(uint4*)&bT[r * LDA + half * 16]     = b0;
                *(uint4*)&bT[r * LDA + half * 16 + 8] = b1;
            }
            __syncthreads();

            bf16x8 afr[TM], bfr[TN];
            #pragma unroll
            for (int tm = 0; tm < TM; ++tm)
                afr[tm] = *(const bf16x8*)&aT[(mbase + tm*16 + l16) * LDA + q * 8];
            #pragma unroll
            for (int tn = 0; tn < TN; ++tn)
                bfr[tn] = *(const bf16x8*)&bT[(cbase + tn*16 + l16) * LDA + q * 8];
            #pragma unroll
            for (int tm = 0; tm < TM; ++tm)
                #pragma unroll
                for (int tn = 0; tn < TN; ++tn)
                    acc[tm][tn] = __builtin_amdgcn_mfma_f32_16x16x32_bf16(
                        afr[tm], bfr[tn], acc[tm][tn], 0, 0, 0);
        }
    }

    // epilogue: C/D layout col=lane&15, row=(lane>>4)*4+reg   [m89-verified]
    #pragma unroll
    for (int tm = 0; tm < TM; ++tm) {
        #pragma unroll
        for (int tn = 0; tn < TN; ++tn) {
            const int col = cbase + tn*16 + l16;
            const float bv = HAS_BIAS ? bias[col] : 0.0f;
            #pragma unroll
            for (int rg = 0; rg < 4; ++rg) {
                const int m = mbase + tm*16 + q*4 + rg;
                const int pix = pixbase + m;
                const int oh = pix >> 5, ow = pix & 31;
                size_t oidx = (((size_t)n_img * Hout + (oh*OS + OPH)) * Wout
                               + (ow*OS + OPW)) * COUT + col;
                float v = acc[tm][tn][rg] + bv;
                if (RESID) v += bf2f(out[oidx]);
                if (RELU_OUT) v = fmaxf(v, 0.0f);
                out[oidx] = f2bf(v);
            }
        }
    }
}

// ---------------- conv1: 3->64 k4 s2 p1, x NCHW fp32 -> NHWC bf16 ----------------
__global__ void conv1_k(const float* __restrict__ x, const float* __restrict__ wT1,
                        const float* __restrict__ b, u16* __restrict__ out)
{
    int tid = blockIdx.x * 256 + threadIdx.x;   // 16,777,216 = 64*64*64*64
    int co = tid & 63;
    int ow = (tid >> 6) & 63;
    int oh = (tid >> 12) & 63;
    int n  = tid >> 18;
    float acc = b[co];
    #pragma unroll
    for (int kh = 0; kh < 4; ++kh) {
        int ih = oh*2 - 1 + kh;
        if ((unsigned)ih >= 128u) continue;
        #pragma unroll
        for (int kw = 0; kw < 4; ++kw) {
            int iw = ow*2 - 1 + kw;
            if ((unsigned)iw >= 128u) continue;
            #pragma unroll
            for (int ci = 0; ci < 3; ++ci) {
                float xv = x[((size_t)(n*3 + ci) << 14) + ih*128 + iw];   // broadcast
                acc = fmaf(xv, wT1[((ci*4 + kh)*4 + kw)*64 + co], acc);   // coalesced
            }
        }
    }
    out[tid] = f2bf(fmaxf(acc, 0.0f));
}

// ---------------- tc2: ConvT 64->3 k4 s2 p1, NHWC bf16 -> NCHW fp32 ----------------
// wT: bf16 [parity][tap][co=3][ci=64]
__global__ void tc2_k(const u16* __restrict__ in, const u16* __restrict__ wT,
                      const float* __restrict__ b, float* __restrict__ out)
{
    int tid = blockIdx.x * 256 + threadIdx.x;   // 1,048,576 = 64*128*128
    int ow = tid & 127, oh = (tid >> 7) & 127, n = tid >> 14;
    int poh = oh & 1, pw = ow & 1, oh2 = oh >> 1, ow2 = ow >> 1;
    int pp = poh*2 + pw;
    float a0 = b[0], a1 = b[1], a2 = b[2];
    #pragma unroll
    for (int ta = 0; ta < 2; ++ta) {
        int ih = oh2 + (poh ? (ta ? 0 : 1) : (ta ? -1 : 0));
        if ((unsigned)ih >= 64u) continue;
        #pragma unroll
        for (int tb = 0; tb < 2; ++tb) {
            int iw = ow2 + (pw ? (tb ? 0 : 1) : (tb ? -1 : 0));
            if ((unsigned)iw >= 64u) continue;
            const u16* src = in + (((size_t)n*64 + ih)*64 + iw)*64;
            const u16* wp  = wT + (size_t)((pp*4 + ta*2 + tb)*3)*64;
            for (int d0 = 0; d0 < 64; d0 += 8) {
                uint4 v = *(const uint4*)(src + d0);
                unsigned ua[4] = {v.x, v.y, v.z, v.w};
                #pragma unroll
                for (int j = 0; j < 4; ++j) {
                    float v0 = bf2f((u16)(ua[j] & 0xFFFFu));
                    float v1 = bf2f((u16)(ua[j] >> 16));
                    int d = d0 + 2*j;
                    a0 = fmaf(v0, bf2f(wp[d]),         a0);
                    a0 = fmaf(v1, bf2f(wp[d+1]),       a0);
                    a1 = fmaf(v0, bf2f(wp[64+d]),      a1);
                    a1 = fmaf(v1, bf2f(wp[64+d+1]),    a1);
                    a2 = fmaf(v0, bf2f(wp[128+d]),     a2);
                    a2 = fmaf(v1, bf2f(wp[128+d+1]),   a2);
                }
            }
        }
    }
    size_t ob = (size_t)n*3*16384 + oh*128 + ow;
    out[ob] = a0; out[ob + 16384] = a1; out[ob + 32768] = a2;
}

// ---------------- vector quantizer ----------------
// Ze NHWC bf16 (65536 x 64); E fp32 (512 x 64); Zq NHWC bf16.
__global__ __launch_bounds__(256)
void vq_k(const u16* __restrict__ Ze, const float* __restrict__ E,
          u16* __restrict__ Zq, float* __restrict__ counts, float* __restrict__ sse)
{
    __shared__ float eld[128 * 64];
    __shared__ float enorm[128];
    __shared__ float red[256];
    int tid = threadIdx.x;
    int p = blockIdx.x * 256 + tid;

    float z[64];
    {
        const u16* zp = Ze + (size_t)p * 64;
        #pragma unroll
        for (int d0 = 0; d0 < 64; d0 += 8) {
            uint4 v = *(const uint4*)(zp + d0);
            unsigned ua[4] = {v.x, v.y, v.z, v.w};
            #pragma unroll
            for (int j = 0; j < 4; ++j) {
                z[d0 + 2*j]     = bf2f((u16)(ua[j] & 0xFFFFu));
                z[d0 + 2*j + 1] = bf2f((u16)(ua[j] >> 16));
            }
        }
    }

    float best = INFINITY; int bestk = 0;
    for (int k0 = 0; k0 < 512; k0 += 128) {
        __syncthreads();
        for (int i = tid*4; i < 8192; i += 1024)
            *(float4*)&eld[i] = *(const float4*)&E[k0*64 + i];
        __syncthreads();
        if (tid < 128) {
            float s = 0;
            #pragma unroll
            for (int d = 0; d < 64; ++d) { float e = eld[tid*64 + d]; s = fmaf(e, e, s); }
            enorm[tid] = s;
        }
        __syncthreads();
        for (int k = 0; k < 128; ++k) {
            const float4* er = (const float4*)&eld[k*64];
            float dot = 0;
            #pragma unroll
            for (int d4 = 0; d4 < 16; ++d4) {
                float4 e4 = er[d4];
                dot = fmaf(z[4*d4+0], e4.x, dot);
                dot = fmaf(z[4*d4+1], e4.y, dot);
                dot = fmaf(z[4*d4+2], e4.z, dot);
                dot = fmaf(z[4*d4+3], e4.w, dot);
            }
            float score = enorm[k] - 2.0f * dot;
            if (score < best) { best = score; bestk = k0 + k; }  // first-min tie-break
        }
    }

    float local = 0;
    const float* eb = E + (size_t)bestk * 64;
    u16* qp = Zq + (size_t)p * 64;
    #pragma unroll
    for (int d = 0; d < 64; ++d) {
        float e = eb[d];
        qp[d] = f2bf(e);
        float df = e - z[d];
        local = fmaf(df, df, local);
    }
    atomicAdd(&counts[bestk], 1.0f);
    red[tid] = local;
    __syncthreads();
    for (int s = 128; s > 0; s >>= 1) {
        if (tid < s) red[tid] += red[tid + s];
        __syncthreads();
    }
    if (tid == 0) atomicAdd(sse, red[0]);
}

// ---------------- weight transforms ----------------
// conv OIHW fp32 -> bf16 [tap][co][ci]
__global__ void wconv_tf_k(const float* __restrict__ w, u16* __restrict__ o,
                           int COUT, int CIN, int KK, int total)
{
    int i = blockIdx.x * 256 + threadIdx.x;
    if (i >= total) return;
    int ci = i % CIN; int t = i / CIN; int co = t % COUT; t /= COUT;
    o[i] = f2bf(w[(co*CIN + ci)*KK + t]);
}
// tc1 (Cin=128,Cout=64,4,4) -> bf16 [parity][tap][co=64][ci=128]
__global__ void wtc1_tf_k(const float* __restrict__ w, u16* __restrict__ o)
{
    int i = blockIdx.x * 256 + threadIdx.x;   // 131072
    if (i >= 131072) return;
    int ci = i & 127; int co = (i >> 7) & 63; int t = (i >> 13) & 3; int p = i >> 15;
    int poh = p >> 1, pw = p & 1; int a = t >> 1, bb = t & 1;
    int kh = poh ? (a ? 2 : 0) : (a ? 3 : 1);
    int kw = pw  ? (bb ? 2 : 0) : (bb ? 3 : 1);
    o[i] = f2bf(w[((ci*64 + co)*4 + kh)*4 + kw]);
}
// tc2 (Cin=64,Cout=3,4,4) -> bf16 [parity][tap][co=3][ci=64]
__global__ void wtc2_tf_k(const float* __restrict__ w, u16* __restrict__ o)
{
    int i = blockIdx.x * 256 + threadIdx.x;   // 3072
    if (i >= 3072) return;
    int ci = i & 63; int co = (i >> 6) % 3; int t = (i / 192) & 3; int p = i / 768;
    int poh = p >> 1, pw = p & 1; int a = t >> 1, bb = t & 1;
    int kh = poh ? (a ? 2 : 0) : (a ? 3 : 1);
    int kw = pw  ? (bb ? 2 : 0) : (bb ? 3 : 1);
    o[i] = f2bf(w[((ci*3 + co)*4 + kh)*4 + kw]);
}
// conv1 (64,3,4,4) fp32 -> fp32 [ci][kh][kw][co]
__global__ void wc1_tf_k(const float* __restrict__ w, float* __restrict__ o)
{
    int i = blockIdx.x * 256 + threadIdx.x;   // 3072
    if (i >= 3072) return;
    int co = i & 63; int kw = (i >> 6) & 3; int kh = (i >> 8) & 3; int ci = i >> 10;
    o[i] = w[((co*3 + ci)*4 + kh)*4 + kw];
}

// ---------------- scalars ----------------
__global__ void finalize_k(const float* __restrict__ counts, const float* __restrict__ sse,
                           float* __restrict__ out_head, float* __restrict__ out_tail)
{
    __shared__ float red[512];
    int t = threadIdx.x;
    float pr = counts[t] / 65536.0f;
    red[t] = -pr * log2f(pr + 1e-10f);
    __syncthreads();
    for (int s = 256; s > 0; s >>= 1) {
        if (t < s) red[t] += red[t + s];
        __syncthreads();
    }
    if (t == 0) {
        float entropy = red[0];
        float mse = sse[0] / 4194304.0f;
        out_head[0] = 1.25f * mse;
        out_tail[0] = mse;
        out_tail[1] = mse;
        out_tail[2] = exp2f(entropy);
    }
}

__global__ void zero_k(float* __restrict__ p, int n)
{
    int i = blockIdx.x * 256 + threadIdx.x;
    if (i < n) p[i] = 0.0f;
}

// ---------------------------------------------------------------------------
extern "C" void kernel_launch(void* const* d_in, const int* in_sizes, int n_in,
                              void* d_out, int out_size, void* d_ws, size_t ws_size,
                              hipStream_t stream)
{
    const float* x         = (const float*)d_in[0];
    const float* enc_w1    = (const float*)d_in[1];
    const float* enc_b1    = (const float*)d_in[2];
    const float* enc_w2    = (const float*)d_in[3];
    const float* enc_b2    = (const float*)d_in[4];
    const float* enc_w3    = (const float*)d_in[5];
    const float* enc_b3    = (const float*)d_in[6];
    const float* enc_w4    = (const float*)d_in[7];
    const float* enc_b4    = (const float*)d_in[8];
    const float* enc_res_w1= (const float*)d_in[9];
    const float* enc_res_w2= (const float*)d_in[10];
    const float* enc_adj_w = (const float*)d_in[11];
    const float* enc_adj_b = (const float*)d_in[12];
    const float* Ecb       = (const float*)d_in[13];
    const float* dec_adj_w = (const float*)d_in[14];
    const float* dec_adj_b = (const float*)d_in[15];
    const float* dec_res_w1= (const float*)d_in[16];
    const float* dec_res_w2= (const float*)d_in[17];
    const float* tc1_w     = (const float*)d_in[18];
    const float* tc1_b     = (const float*)d_in[19];
    const float* tc2_w     = (const float*)d_in[20];
    const float* tc2_b     = (const float*)d_in[21];

    char* wsb = (char*)d_ws;
    u16*   wc2   = (u16*)(wsb + 0);
    u16*   wc3   = (u16*)(wsb + 262144);
    u16*   wc4   = (u16*)(wsb + 557056);
    u16*   wer1  = (u16*)(wsb + 851968);
    u16*   wer2  = (u16*)(wsb + 1146880);
    u16*   weadj = (u16*)(wsb + 1179648);
    u16*   wdadj = (u16*)(wsb + 1196032);
    u16*   wdr1  = (u16*)(wsb + 1343488);
    u16*   wdr2  = (u16*)(wsb + 1638400);
    u16*   wtc1  = (u16*)(wsb + 1671168);
    u16*   wtc2  = (u16*)(wsb + 1933312);
    float* wc1   = (float*)(wsb + 1939456);
    float* counts= (float*)(wsb + 1951744);
    float* sse   = counts + 512;
    u16*   H1    = (u16*)(wsb + 2097152);
    u16*   TR    = (u16*)(wsb + 35651584);
    u16*   H3    = (u16*)(wsb + 52428800);
    u16*   MID   = (u16*)(wsb + 69206016);
    u16*   ZE    = (u16*)(wsb + 77594624);
    u16*   ZQ    = (u16*)(wsb + 85983232);
    u16*   TC1O  = H1;   // h1 dead after conv2

    float* out  = (float*)d_out;
    float* xrec = out + 1;
    float* tail = out + 1 + 3145728;

    // tap tables
    Taps t3x3; t3x3.s = 1; t3x3.ntaps = 9;
    for (int kh = 0; kh < 3; ++kh) for (int kw = 0; kw < 3; ++kw) {
        t3x3.dh[kh*3+kw] = kh - 1; t3x3.dw[kh*3+kw] = kw - 1;
    }
    Taps t1x1; t1x1.s = 1; t1x1.ntaps = 1; t1x1.dh[0] = 0; t1x1.dw[0] = 0;
    Taps t4x4; t4x4.s = 2; t4x4.ntaps = 16;
    for (int kh = 0; kh < 4; ++kh) for (int kw = 0; kw < 4; ++kw) {
        t4x4.dh[kh*4+kw] = kh - 1; t4x4.dw[kh*4+kw] = kw - 1;
    }
    const int dtab[2][2] = {{0, -1}, {1, 0}};
    Taps ttc1[4];
    for (int p = 0; p < 4; ++p) {
        ttc1[p].s = 1; ttc1[p].ntaps = 4;
        for (int a = 0; a < 2; ++a) for (int bb = 0; bb < 2; ++bb) {
            ttc1[p].dh[a*2+bb] = dtab[p>>1][a];
            ttc1[p].dw[a*2+bb] = dtab[p&1][bb];
        }
    }

    // ---- weight transforms + accumulator zero ----
    zero_k<<<3, 256, 0, stream>>>(counts, 513);
    wc1_tf_k<<<12, 256, 0, stream>>>(enc_w1, wc1);
    wconv_tf_k<<<512, 256, 0, stream>>>(enc_w2, wc2, 128, 64, 16, 131072);
    wconv_tf_k<<<576, 256, 0, stream>>>(enc_w3, wc3, 128, 128, 9, 147456);
    wconv_tf_k<<<576, 256, 0, stream>>>(enc_w4, wc4, 128, 128, 9, 147456);
    for (int i = 0; i < 2; ++i) {
        wconv_tf_k<<<288, 256, 0, stream>>>(enc_res_w1 + i*73728, wer1 + i*73728, 64, 128, 9, 73728);
        wconv_tf_k<<<32,  256, 0, stream>>>(enc_res_w2 + i*8192,  wer2 + i*8192,  128, 64, 1, 8192);
        wconv_tf_k<<<288, 256, 0, stream>>>(dec_res_w1 + i*73728, wdr1 + i*73728, 64, 128, 9, 73728);
        wconv_tf_k<<<32,  256, 0, stream>>>(dec_res_w2 + i*8192,  wdr2 + i*8192,  128, 64, 1, 8192);
    }
    wconv_tf_k<<<32,  256, 0, stream>>>(enc_adj_w, weadj, 64, 128, 1, 8192);
    wconv_tf_k<<<288, 256, 0, stream>>>(dec_adj_w, wdadj, 128, 64, 9, 73728);
    wtc1_tf_k<<<512, 256, 0, stream>>>(tc1_w, wtc1);
    wtc2_tf_k<<<12,  256, 0, stream>>>(tc2_w, wtc2);

    // ---- encoder ----
    conv1_k<<<65536, 256, 0, stream>>>(x, wc1, enc_b1, H1);
    mfma_conv_k<64,128,false,true,true,false><<<512, 256, 0, stream>>>
        (H1, wc2, enc_b2, TR, 64, 64, 32, 32, 1, 0, 0, t4x4);
    mfma_conv_k<128,128,false,true,true,false><<<512, 256, 0, stream>>>
        (TR, wc3, enc_b3, H3, 32, 32, 32, 32, 1, 0, 0, t3x3);
    mfma_conv_k<128,128,false,false,true,false><<<512, 256, 0, stream>>>
        (H3, wc4, enc_b4, TR, 32, 32, 32, 32, 1, 0, 0, t3x3);
    for (int i = 0; i < 2; ++i) {
        mfma_conv_k<128,64,true,false,false,false><<<512, 256, 0, stream>>>
            (TR, wer1 + i*73728, nullptr, MID, 32, 32, 32, 32, 1, 0, 0, t3x3);
        mfma_conv_k<64,128,true,false,false,true><<<512, 256, 0, stream>>>
            (MID, wer2 + i*8192, nullptr, TR, 32, 32, 32, 32, 1, 0, 0, t1x1);
    }
    mfma_conv_k<128,64,true,false,true,false><<<512, 256, 0, stream>>>
        (TR, weadj, enc_adj_b, ZE, 32, 32, 32, 32, 1, 0, 0, t1x1);

    // ---- VQ ----
    vq_k<<<256, 256, 0, stream>>>(ZE, Ecb, ZQ, counts, sse);

    // ---- decoder ----
    mfma_conv_k<64,128,false,false,true,false><<<512, 256, 0, stream>>>
        (ZQ, wdadj, dec_adj_b, H3, 32, 32, 32, 32, 1, 0, 0, t3x3);
    for (int i = 0; i < 2; ++i) {
        mfma_conv_k<128,64,true,false,false,false><<<512, 256, 0, stream>>>
            (H3, wdr1 + i*73728, nullptr, MID, 32, 32, 32, 32, 1, 0, 0, t3x3);
        mfma_conv_k<64,128,true,false,false,true><<<512, 256, 0, stream>>>
            (MID, wdr2 + i*8192, nullptr, H3, 32, 32, 32, 32, 1, 0, 0, t1x1);
    }
    for (int p = 0; p < 4; ++p) {
        mfma_conv_k<128,64,true,true,true,false><<<512, 256, 0, stream>>>
            (H3, wtc1 + p*32768, tc1_b, TC1O, 32, 32, 64, 64, 2, p>>1, p&1, ttc1[p]);
    }
    tc2_k<<<4096, 256, 0, stream>>>(TC1O, wtc2, tc2_b, xrec);

    // ---- scalars ----
    finalize_k<<<1, 512, 0, stream>>>(counts, sse, out, tail);
}

// Round 3
// 1340.353 us; speedup vs baseline: 19.1220x; 1.1711x over previous
//
#include <hip/hip_runtime.h>
#include <math.h>

// ---------------------------------------------------------------------------
// VQ-VAE forward: NHWC bf16 trunk, implicit-GEMM MFMA convs (fp32 accum),
// MFMA-based vector quantizer.
//
// Workspace layout (bytes):
//   [0 .. ~2.0MB)   transformed weights + wc1 fp32 + counts/sse + Ebf + enorm
//   H1  = 2097152   (64,64,64,64)  NHWC bf16  33.5MB   h1, later tc1 out
//   TR  = 35651584  (64,32,32,128) NHWC bf16  16.8MB   enc trunk
//   H3  = 52428800  (64,32,32,128) NHWC bf16  16.8MB   h3, later dec trunk
//   MID = 69206016  (64,32,32,64)  NHWC bf16   8.4MB   res mid
//   ZE  = 77594624  (64,32,32,64)  NHWC bf16   8.4MB
//   ZQ  = 85983232  (64,32,32,64)  NHWC bf16   8.4MB
// ---------------------------------------------------------------------------

typedef unsigned short u16;
typedef __attribute__((ext_vector_type(8))) short bf16x8;
typedef __attribute__((ext_vector_type(4))) float f32x4;

__device__ __forceinline__ float bf2f(u16 h) {
    union { unsigned u; float f; } v; v.u = ((unsigned)h) << 16; return v.f;
}
__device__ __forceinline__ u16 f2bf(float f) {
    union { float f; unsigned u; } v; v.f = f;
    unsigned r = v.u + 0x7FFFu + ((v.u >> 16) & 1u);
    return (u16)(r >> 16);
}
// packed relu on 2 bf16 halves of a uint
__device__ __forceinline__ unsigned relu2(unsigned x) {
    return x & ~(((x & 0x80008000u) >> 15) * 0xFFFFu);
}

struct Taps { int s; int ntaps; int dh[16]; int dw[16]; };

// ---------------- unified implicit-GEMM MFMA conv ----------------
template<int CIN, int COUT, bool RELU_IN, bool RELU_OUT, bool HAS_BIAS, bool RESID>
__global__ __launch_bounds__(256)
void mfma_conv_k(const u16* __restrict__ in, const u16* __restrict__ wT,
                 const float* __restrict__ bias, u16* __restrict__ out,
                 int Hin, int Win, int Hout, int Wout, int OS, int OPH, int OPW,
                 Taps taps)
{
    constexpr int WN = (COUT == 128) ? 2 : 1;
    constexpr int WM = 4 / WN;
    constexpr int TM = (128 / WM) / 16;
    constexpr int TN = (COUT / WN) / 16;
    constexpr int LDA = 40;  // 32 data + 8 pad

    __shared__ alignas(16) u16 aT[128 * LDA];
    __shared__ alignas(16) u16 bT[COUT * LDA];

    const int tid = threadIdx.x;
    const int m0 = blockIdx.x * 128;
    const int n_img = m0 >> 10;
    const int pixbase = m0 & 1023;

    const int r = tid >> 1, half = tid & 1;
    const int pr = pixbase + r;
    const int ohr = pr >> 5, owr = pr & 31;
    const u16* inb = in + (size_t)n_img * Hin * Win * CIN;

    const int wv = tid >> 6, lane = tid & 63;
    const int q = lane >> 4, l16 = lane & 15;
    const int wm = wv / WN, wn = wv % WN;
    const int mbase = wm * (TM * 16), cbase = wn * (TN * 16);

    f32x4 acc[TM][TN] = {};

    for (int t = 0; t < taps.ntaps; ++t) {
        const int ih = ohr * taps.s + taps.dh[t];
        const int iw = owr * taps.s + taps.dw[t];
        const bool ok = ((unsigned)ih < (unsigned)Hin) && ((unsigned)iw < (unsigned)Win);
        const u16* asrc = ok ? (inb + ((size_t)ih * Win + iw) * CIN + half * 16) : inb;
        const u16* bsrc = wT + ((size_t)t * COUT + r) * CIN + half * 16;

        for (int c0 = 0; c0 < CIN; c0 += 32) {
            __syncthreads();
            uint4 a0 = {0,0,0,0}, a1 = {0,0,0,0};
            if (ok) {
                a0 = *(const uint4*)(asrc + c0);
                a1 = *(const uint4*)(asrc + c0 + 8);
            }
            if (RELU_IN) {
                a0.x = relu2(a0.x); a0.y = relu2(a0.y); a0.z = relu2(a0.z); a0.w = relu2(a0.w);
                a1.x = relu2(a1.x); a1.y = relu2(a1.y); a1.z = relu2(a1.z); a1.w = relu2(a1.w);
            }
            *(uint4*)&aT[r * LDA + half * 16]     = a0;
            *(uint4*)&aT[r * LDA + half * 16 + 8] = a1;
            if (COUT == 128 || r < COUT) {
                uint4 b0 = *(const uint4*)(bsrc + c0);
                uint4 b1 = *(const uint4*)(bsrc + c0 + 8);
                *(uint4*)&bT[r * LDA + half * 16]     = b0;
                *(uint4*)&bT[r * LDA + half * 16 + 8] = b1;
            }
            __syncthreads();

            bf16x8 afr[TM], bfr[TN];
            #pragma unroll
            for (int tm = 0; tm < TM; ++tm)
                afr[tm] = *(const bf16x8*)&aT[(mbase + tm*16 + l16) * LDA + q * 8];
            #pragma unroll
            for (int tn = 0; tn < TN; ++tn)
                bfr[tn] = *(const bf16x8*)&bT[(cbase + tn*16 + l16) * LDA + q * 8];
            #pragma unroll
            for (int tm = 0; tm < TM; ++tm)
                #pragma unroll
                for (int tn = 0; tn < TN; ++tn)
                    acc[tm][tn] = __builtin_amdgcn_mfma_f32_16x16x32_bf16(
                        afr[tm], bfr[tn], acc[tm][tn], 0, 0, 0);
        }
    }

    #pragma unroll
    for (int tm = 0; tm < TM; ++tm) {
        #pragma unroll
        for (int tn = 0; tn < TN; ++tn) {
            const int col = cbase + tn*16 + l16;
            const float bv = HAS_BIAS ? bias[col] : 0.0f;
            #pragma unroll
            for (int rg = 0; rg < 4; ++rg) {
                const int m = mbase + tm*16 + q*4 + rg;
                const int pix = pixbase + m;
                const int oh = pix >> 5, ow = pix & 31;
                size_t oidx = (((size_t)n_img * Hout + (oh*OS + OPH)) * Wout
                               + (ow*OS + OPW)) * COUT + col;
                float v = acc[tm][tn][rg] + bv;
                if (RESID) v += bf2f(out[oidx]);
                if (RELU_OUT) v = fmaxf(v, 0.0f);
                out[oidx] = f2bf(v);
            }
        }
    }
}

// ---------------- conv1: 3->64 k4 s2 p1, x NCHW fp32 -> NHWC bf16 ----------------
__global__ void conv1_k(const float* __restrict__ x, const float* __restrict__ wT1,
                        const float* __restrict__ b, u16* __restrict__ out)
{
    int tid = blockIdx.x * 256 + threadIdx.x;
    int co = tid & 63;
    int ow = (tid >> 6) & 63;
    int oh = (tid >> 12) & 63;
    int n  = tid >> 18;
    float acc = b[co];
    #pragma unroll
    for (int kh = 0; kh < 4; ++kh) {
        int ih = oh*2 - 1 + kh;
        if ((unsigned)ih >= 128u) continue;
        #pragma unroll
        for (int kw = 0; kw < 4; ++kw) {
            int iw = ow*2 - 1 + kw;
            if ((unsigned)iw >= 128u) continue;
            #pragma unroll
            for (int ci = 0; ci < 3; ++ci) {
                float xv = x[((size_t)(n*3 + ci) << 14) + ih*128 + iw];
                acc = fmaf(xv, wT1[((ci*4 + kh)*4 + kw)*64 + co], acc);
            }
        }
    }
    out[tid] = f2bf(fmaxf(acc, 0.0f));
}

// ---------------- tc2: ConvT 64->3 k4 s2 p1, NHWC bf16 -> NCHW fp32 ----------------
__global__ void tc2_k(const u16* __restrict__ in, const u16* __restrict__ wT,
                      const float* __restrict__ b, float* __restrict__ out)
{
    int tid = blockIdx.x * 256 + threadIdx.x;
    int ow = tid & 127, oh = (tid >> 7) & 127, n = tid >> 14;
    int poh = oh & 1, pw = ow & 1, oh2 = oh >> 1, ow2 = ow >> 1;
    int pp = poh*2 + pw;
    float a0 = b[0], a1 = b[1], a2 = b[2];
    #pragma unroll
    for (int ta = 0; ta < 2; ++ta) {
        int ih = oh2 + (poh ? (ta ? 0 : 1) : (ta ? -1 : 0));
        if ((unsigned)ih >= 64u) continue;
        #pragma unroll
        for (int tb = 0; tb < 2; ++tb) {
            int iw = ow2 + (pw ? (tb ? 0 : 1) : (tb ? -1 : 0));
            if ((unsigned)iw >= 64u) continue;
            const u16* src = in + (((size_t)n*64 + ih)*64 + iw)*64;
            const u16* wp  = wT + (size_t)((pp*4 + ta*2 + tb)*3)*64;
            for (int d0 = 0; d0 < 64; d0 += 8) {
                uint4 v = *(const uint4*)(src + d0);
                unsigned ua[4] = {v.x, v.y, v.z, v.w};
                #pragma unroll
                for (int j = 0; j < 4; ++j) {
                    float v0 = bf2f((u16)(ua[j] & 0xFFFFu));
                    float v1 = bf2f((u16)(ua[j] >> 16));
                    int d = d0 + 2*j;
                    a0 = fmaf(v0, bf2f(wp[d]),         a0);
                    a0 = fmaf(v1, bf2f(wp[d+1]),       a0);
                    a1 = fmaf(v0, bf2f(wp[64+d]),      a1);
                    a1 = fmaf(v1, bf2f(wp[64+d+1]),    a1);
                    a2 = fmaf(v0, bf2f(wp[128+d]),     a2);
                    a2 = fmaf(v1, bf2f(wp[128+d+1]),   a2);
                }
            }
        }
    }
    size_t ob = (size_t)n*3*16384 + oh*128 + ow;
    out[ob] = a0; out[ob + 16384] = a1; out[ob + 32768] = a2;
}

// ---------------- VQ: E prep (bf16 convert + norms of bf16-rounded values) ----
__global__ void eprep_k(const float* __restrict__ E, u16* __restrict__ Ebf,
                        float* __restrict__ enorm)
{
    int k = blockIdx.x * 256 + threadIdx.x;   // 512 codes
    if (k >= 512) return;
    float s = 0.0f;
    #pragma unroll
    for (int d = 0; d < 64; ++d) {
        u16 h = f2bf(E[k*64 + d]);
        Ebf[k*64 + d] = h;
        float v = bf2f(h);
        s = fmaf(v, v, s);
    }
    enorm[k] = s;
}

// ---------------- MFMA vector quantizer ----------------
// One wave = 16 positions x all 512 codes.  Block = 4 waves = 64 positions.
// score = ||e||^2 - 2 z.e ; argmin, first-min tie-break (ascending cols per
// lane, idx tie-break in the cross-lane reduce).
__global__ __launch_bounds__(256)
void vq_mfma_k(const u16* __restrict__ Ze, const u16* __restrict__ Ebf,
               const float* __restrict__ enorm, u16* __restrict__ Zq,
               float* __restrict__ counts, float* __restrict__ sse)
{
    __shared__ int bestk_s[64];
    __shared__ float red[256];
    const int tid = threadIdx.x;
    const int lane = tid & 63, wv = tid >> 6;
    const int q = lane >> 4, l16 = lane & 15;
    const int p0 = blockIdx.x * 64 + wv * 16;

    // A fragments: rows = positions p0+l16; A[m=l16][k=q*8+j] per 32-k slice
    bf16x8 a0 = *(const bf16x8*)(Ze + (size_t)(p0 + l16) * 64 + q * 8);
    bf16x8 a1 = *(const bf16x8*)(Ze + (size_t)(p0 + l16) * 64 + 32 + q * 8);

    float best[4] = {INFINITY, INFINITY, INFINITY, INFINITY};
    int bk[4] = {0, 0, 0, 0};

    for (int t = 0; t < 32; ++t) {
        const int n = t * 16 + l16;
        bf16x8 b0 = *(const bf16x8*)(Ebf + (size_t)n * 64 + q * 8);
        bf16x8 b1 = *(const bf16x8*)(Ebf + (size_t)n * 64 + 32 + q * 8);
        f32x4 acc = {0.0f, 0.0f, 0.0f, 0.0f};
        acc = __builtin_amdgcn_mfma_f32_16x16x32_bf16(a0, b0, acc, 0, 0, 0);
        acc = __builtin_amdgcn_mfma_f32_16x16x32_bf16(a1, b1, acc, 0, 0, 0);
        const float en = enorm[n];   // col for this lane = n
        #pragma unroll
        for (int rg = 0; rg < 4; ++rg) {
            float sc = en - 2.0f * acc[rg];
            if (sc < best[rg]) { best[rg] = sc; bk[rg] = n; }
        }
    }

    // cross-lane argmin over the 16 cols held by l16-group (rows = q*4+rg)
    #pragma unroll
    for (int m = 1; m < 16; m <<= 1) {
        #pragma unroll
        for (int rg = 0; rg < 4; ++rg) {
            float os = __shfl_xor(best[rg], m, 64);
            int   ok = __shfl_xor(bk[rg], m, 64);
            if (os < best[rg] || (os == best[rg] && ok < bk[rg])) {
                best[rg] = os; bk[rg] = ok;
            }
        }
    }
    if (l16 == 0) {
        #pragma unroll
        for (int rg = 0; rg < 4; ++rg)
            bestk_s[wv * 16 + q * 4 + rg] = bk[rg];
    }
    __syncthreads();

    // cooperative Zq write (32B/thread, coalesced) + SSE + counts
    const int pos = tid >> 2, seg = tid & 3;
    const int p = blockIdx.x * 64 + pos;
    const int k = bestk_s[pos];
    const u16* ep = Ebf + (size_t)k * 64 + seg * 16;
    const u16* zp = Ze + (size_t)p * 64 + seg * 16;
    u16* qp = Zq + (size_t)p * 64 + seg * 16;
    float local = 0.0f;
    #pragma unroll
    for (int h = 0; h < 2; ++h) {
        uint4 ev = *(const uint4*)(ep + h * 8);
        uint4 zv = *(const uint4*)(zp + h * 8);
        *(uint4*)(qp + h * 8) = ev;
        unsigned ea[4] = {ev.x, ev.y, ev.z, ev.w};
        unsigned za[4] = {zv.x, zv.y, zv.z, zv.w};
        #pragma unroll
        for (int j = 0; j < 4; ++j) {
            float d0 = bf2f((u16)(ea[j] & 0xFFFFu)) - bf2f((u16)(za[j] & 0xFFFFu));
            float d1 = bf2f((u16)(ea[j] >> 16))     - bf2f((u16)(za[j] >> 16));
            local = fmaf(d0, d0, fmaf(d1, d1, local));
        }
    }
    if (seg == 0) atomicAdd(&counts[k], 1.0f);
    red[tid] = local;
    __syncthreads();
    for (int s = 128; s > 0; s >>= 1) {
        if (tid < s) red[tid] += red[tid + s];
        __syncthreads();
    }
    if (tid == 0) atomicAdd(sse, red[0]);
}

// ---------------- weight transforms ----------------
__global__ void wconv_tf_k(const float* __restrict__ w, u16* __restrict__ o,
                           int COUT, int CIN, int KK, int total)
{
    int i = blockIdx.x * 256 + threadIdx.x;
    if (i >= total) return;
    int ci = i % CIN; int t = i / CIN; int co = t % COUT; t /= COUT;
    o[i] = f2bf(w[(co*CIN + ci)*KK + t]);
}
__global__ void wtc1_tf_k(const float* __restrict__ w, u16* __restrict__ o)
{
    int i = blockIdx.x * 256 + threadIdx.x;
    if (i >= 131072) return;
    int ci = i & 127; int co = (i >> 7) & 63; int t = (i >> 13) & 3; int p = i >> 15;
    int poh = p >> 1, pw = p & 1; int a = t >> 1, bb = t & 1;
    int kh = poh ? (a ? 2 : 0) : (a ? 3 : 1);
    int kw = pw  ? (bb ? 2 : 0) : (bb ? 3 : 1);
    o[i] = f2bf(w[((ci*64 + co)*4 + kh)*4 + kw]);
}
__global__ void wtc2_tf_k(const float* __restrict__ w, u16* __restrict__ o)
{
    int i = blockIdx.x * 256 + threadIdx.x;
    if (i >= 3072) return;
    int ci = i & 63; int co = (i >> 6) % 3; int t = (i / 192) & 3; int p = i / 768;
    int poh = p >> 1, pw = p & 1; int a = t >> 1, bb = t & 1;
    int kh = poh ? (a ? 2 : 0) : (a ? 3 : 1);
    int kw = pw  ? (bb ? 2 : 0) : (bb ? 3 : 1);
    o[i] = f2bf(w[((ci*3 + co)*4 + kh)*4 + kw]);
}
__global__ void wc1_tf_k(const float* __restrict__ w, float* __restrict__ o)
{
    int i = blockIdx.x * 256 + threadIdx.x;
    if (i >= 3072) return;
    int co = i & 63; int kw = (i >> 6) & 3; int kh = (i >> 8) & 3; int ci = i >> 10;
    o[i] = w[((co*3 + ci)*4 + kh)*4 + kw];
}

// ---------------- scalars ----------------
__global__ void finalize_k(const float* __restrict__ counts, const float* __restrict__ sse,
                           float* __restrict__ out_head, float* __restrict__ out_tail)
{
    __shared__ float red[512];
    int t = threadIdx.x;
    float pr = counts[t] / 65536.0f;
    red[t] = -pr * log2f(pr + 1e-10f);
    __syncthreads();
    for (int s = 256; s > 0; s >>= 1) {
        if (t < s) red[t] += red[t + s];
        __syncthreads();
    }
    if (t == 0) {
        float entropy = red[0];
        float mse = sse[0] / 4194304.0f;
        out_head[0] = 1.25f * mse;
        out_tail[0] = mse;
        out_tail[1] = mse;
        out_tail[2] = exp2f(entropy);
    }
}

__global__ void zero_k(float* __restrict__ p, int n)
{
    int i = blockIdx.x * 256 + threadIdx.x;
    if (i < n) p[i] = 0.0f;
}

// ---------------------------------------------------------------------------
extern "C" void kernel_launch(void* const* d_in, const int* in_sizes, int n_in,
                              void* d_out, int out_size, void* d_ws, size_t ws_size,
                              hipStream_t stream)
{
    const float* x         = (const float*)d_in[0];
    const float* enc_w1    = (const float*)d_in[1];
    const float* enc_b1    = (const float*)d_in[2];
    const float* enc_w2    = (const float*)d_in[3];
    const float* enc_b2    = (const float*)d_in[4];
    const float* enc_w3    = (const float*)d_in[5];
    const float* enc_b3    = (const float*)d_in[6];
    const float* enc_w4    = (const float*)d_in[7];
    const float* enc_b4    = (const float*)d_in[8];
    const float* enc_res_w1= (const float*)d_in[9];
    const float* enc_res_w2= (const float*)d_in[10];
    const float* enc_adj_w = (const float*)d_in[11];
    const float* enc_adj_b = (const float*)d_in[12];
    const float* Ecb       = (const float*)d_in[13];
    const float* dec_adj_w = (const float*)d_in[14];
    const float* dec_adj_b = (const float*)d_in[15];
    const float* dec_res_w1= (const float*)d_in[16];
    const float* dec_res_w2= (const float*)d_in[17];
    const float* tc1_w     = (const float*)d_in[18];
    const float* tc1_b     = (const float*)d_in[19];
    const float* tc2_w     = (const float*)d_in[20];
    const float* tc2_b     = (const float*)d_in[21];

    char* wsb = (char*)d_ws;
    u16*   wc2   = (u16*)(wsb + 0);
    u16*   wc3   = (u16*)(wsb + 262144);
    u16*   wc4   = (u16*)(wsb + 557056);
    u16*   wer1  = (u16*)(wsb + 851968);
    u16*   wer2  = (u16*)(wsb + 1146880);
    u16*   weadj = (u16*)(wsb + 1179648);
    u16*   wdadj = (u16*)(wsb + 1196032);
    u16*   wdr1  = (u16*)(wsb + 1343488);
    u16*   wdr2  = (u16*)(wsb + 1638400);
    u16*   wtc1  = (u16*)(wsb + 1671168);
    u16*   wtc2  = (u16*)(wsb + 1933312);
    float* wc1   = (float*)(wsb + 1939456);
    float* counts= (float*)(wsb + 1951744);
    float* sse   = counts + 512;
    u16*   Ebf   = (u16*)(wsb + 1955840);   // 64 KB
    float* enorm = (float*)(wsb + 2021376); // 2 KB
    u16*   H1    = (u16*)(wsb + 2097152);
    u16*   TR    = (u16*)(wsb + 35651584);
    u16*   H3    = (u16*)(wsb + 52428800);
    u16*   MID   = (u16*)(wsb + 69206016);
    u16*   ZE    = (u16*)(wsb + 77594624);
    u16*   ZQ    = (u16*)(wsb + 85983232);
    u16*   TC1O  = H1;

    float* out  = (float*)d_out;
    float* xrec = out + 1;
    float* tail = out + 1 + 3145728;

    Taps t3x3; t3x3.s = 1; t3x3.ntaps = 9;
    for (int kh = 0; kh < 3; ++kh) for (int kw = 0; kw < 3; ++kw) {
        t3x3.dh[kh*3+kw] = kh - 1; t3x3.dw[kh*3+kw] = kw - 1;
    }
    Taps t1x1; t1x1.s = 1; t1x1.ntaps = 1; t1x1.dh[0] = 0; t1x1.dw[0] = 0;
    Taps t4x4; t4x4.s = 2; t4x4.ntaps = 16;
    for (int kh = 0; kh < 4; ++kh) for (int kw = 0; kw < 4; ++kw) {
        t4x4.dh[kh*4+kw] = kh - 1; t4x4.dw[kh*4+kw] = kw - 1;
    }
    const int dtab[2][2] = {{0, -1}, {1, 0}};
    Taps ttc1[4];
    for (int p = 0; p < 4; ++p) {
        ttc1[p].s = 1; ttc1[p].ntaps = 4;
        for (int a = 0; a < 2; ++a) for (int bb = 0; bb < 2; ++bb) {
            ttc1[p].dh[a*2+bb] = dtab[p>>1][a];
            ttc1[p].dw[a*2+bb] = dtab[p&1][bb];
        }
    }

    // ---- weight transforms + accumulator zero ----
    zero_k<<<3, 256, 0, stream>>>(counts, 513);
    wc1_tf_k<<<12, 256, 0, stream>>>(enc_w1, wc1);
    wconv_tf_k<<<512, 256, 0, stream>>>(enc_w2, wc2, 128, 64, 16, 131072);
    wconv_tf_k<<<576, 256, 0, stream>>>(enc_w3, wc3, 128, 128, 9, 147456);
    wconv_tf_k<<<576, 256, 0, stream>>>(enc_w4, wc4, 128, 128, 9, 147456);
    for (int i = 0; i < 2; ++i) {
        wconv_tf_k<<<288, 256, 0, stream>>>(enc_res_w1 + i*73728, wer1 + i*73728, 64, 128, 9, 73728);
        wconv_tf_k<<<32,  256, 0, stream>>>(enc_res_w2 + i*8192,  wer2 + i*8192,  128, 64, 1, 8192);
        wconv_tf_k<<<288, 256, 0, stream>>>(dec_res_w1 + i*73728, wdr1 + i*73728, 64, 128, 9, 73728);
        wconv_tf_k<<<32,  256, 0, stream>>>(dec_res_w2 + i*8192,  wdr2 + i*8192,  128, 64, 1, 8192);
    }
    wconv_tf_k<<<32,  256, 0, stream>>>(enc_adj_w, weadj, 64, 128, 1, 8192);
    wconv_tf_k<<<288, 256, 0, stream>>>(dec_adj_w, wdadj, 128, 64, 9, 73728);
    wtc1_tf_k<<<512, 256, 0, stream>>>(tc1_w, wtc1);
    wtc2_tf_k<<<12,  256, 0, stream>>>(tc2_w, wtc2);
    eprep_k<<<2, 256, 0, stream>>>(Ecb, Ebf, enorm);

    // ---- encoder ----
    conv1_k<<<65536, 256, 0, stream>>>(x, wc1, enc_b1, H1);
    mfma_conv_k<64,128,false,true,true,false><<<512, 256, 0, stream>>>
        (H1, wc2, enc_b2, TR, 64, 64, 32, 32, 1, 0, 0, t4x4);
    mfma_conv_k<128,128,false,true,true,false><<<512, 256, 0, stream>>>
        (TR, wc3, enc_b3, H3, 32, 32, 32, 32, 1, 0, 0, t3x3);
    mfma_conv_k<128,128,false,false,true,false><<<512, 256, 0, stream>>>
        (H3, wc4, enc_b4, TR, 32, 32, 32, 32, 1, 0, 0, t3x3);
    for (int i = 0; i < 2; ++i) {
        mfma_conv_k<128,64,true,false,false,false><<<512, 256, 0, stream>>>
            (TR, wer1 + i*73728, nullptr, MID, 32, 32, 32, 32, 1, 0, 0, t3x3);
        mfma_conv_k<64,128,true,false,false,true><<<512, 256, 0, stream>>>
            (MID, wer2 + i*8192, nullptr, TR, 32, 32, 32, 32, 1, 0, 0, t1x1);
    }
    mfma_conv_k<128,64,true,false,true,false><<<512, 256, 0, stream>>>
        (TR, weadj, enc_adj_b, ZE, 32, 32, 32, 32, 1, 0, 0, t1x1);

    // ---- VQ ----
    vq_mfma_k<<<1024, 256, 0, stream>>>(ZE, Ebf, enorm, ZQ, counts, sse);

    // ---- decoder ----
    mfma_conv_k<64,128,false,false,true,false><<<512, 256, 0, stream>>>
        (ZQ, wdadj, dec_adj_b, H3, 32, 32, 32, 32, 1, 0, 0, t3x3);
    for (int i = 0; i < 2; ++i) {
        mfma_conv_k<128,64,true,false,false,false><<<512, 256, 0, stream>>>
            (H3, wdr1 + i*73728, nullptr, MID, 32, 32, 32, 32, 1, 0, 0, t3x3);
        mfma_conv_k<64,128,true,false,false,true><<<512, 256, 0, stream>>>
            (MID, wdr2 + i*8192, nullptr, H3, 32, 32, 32, 32, 1, 0, 0, t1x1);
    }
    for (int p = 0; p < 4; ++p) {
        mfma_conv_k<128,64,true,true,true,false><<<512, 256, 0, stream>>>
            (H3, wtc1 + p*32768, tc1_b, TC1O, 32, 32, 64, 64, 2, p>>1, p&1, ttc1[p]);
    }
    tc2_k<<<4096, 256, 0, stream>>>(TC1O, wtc2, tc2_b, xrec);

    // ---- scalars ----
    finalize_k<<<1, 512, 0, stream>>>(counts, sse, out, tail);
}

// Round 4
// 927.830 us; speedup vs baseline: 27.6238x; 1.4446x over previous
//
#include <hip/hip_runtime.h>
#include <math.h>

// ---------------------------------------------------------------------------
// VQ-VAE forward: NHWC bf16 trunk, implicit-GEMM MFMA convs (fp32 accum),
// MFMA vector quantizer (no per-position atomics; histogram by scan).
//
// Workspace layout (bytes):
//   [0 .. ~2.0MB)   transformed weights + wc1 fp32 + counts/sse + Ebf + enorm
//   H1  = 2097152   (64,64,64,64)  NHWC bf16  33.5MB   h1, later tc1 out
//   TR  = 35651584  (64,32,32,128) NHWC bf16  16.8MB   enc trunk
//   H3  = 52428800  (64,32,32,128) NHWC bf16  16.8MB   h3, later dec trunk
//   MID = 69206016  (64,32,32,64)  NHWC bf16   8.4MB   res mid
//   ZE  = 77594624  (64,32,32,64)  NHWC bf16   8.4MB
//   ZQ  = 85983232  (64,32,32,64)  NHWC bf16   8.4MB
//   IDX = 94371840  65536 u16      128KB
// ---------------------------------------------------------------------------

typedef unsigned short u16;
typedef __attribute__((ext_vector_type(8))) short bf16x8;
typedef __attribute__((ext_vector_type(4))) float f32x4;

__device__ __forceinline__ float bf2f(u16 h) {
    union { unsigned u; float f; } v; v.u = ((unsigned)h) << 16; return v.f;
}
__device__ __forceinline__ u16 f2bf(float f) {
    union { float f; unsigned u; } v; v.f = f;
    unsigned r = v.u + 0x7FFFu + ((v.u >> 16) & 1u);
    return (u16)(r >> 16);
}
__device__ __forceinline__ unsigned relu2(unsigned x) {
    return x & ~(((x & 0x80008000u) >> 15) * 0xFFFFu);
}

struct Taps { int s; int ntaps; int dh[16]; int dw[16]; };

// ---------------- unified implicit-GEMM MFMA conv ----------------
template<int CIN, int COUT, bool RELU_IN, bool RELU_OUT, bool HAS_BIAS, bool RESID>
__global__ __launch_bounds__(256)
void mfma_conv_k(const u16* __restrict__ in, const u16* __restrict__ wT,
                 const float* __restrict__ bias, u16* __restrict__ out,
                 int Hin, int Win, int Hout, int Wout, int OS, int OPH, int OPW,
                 Taps taps)
{
    constexpr int WN = (COUT == 128) ? 2 : 1;
    constexpr int WM = 4 / WN;
    constexpr int TM = (128 / WM) / 16;
    constexpr int TN = (COUT / WN) / 16;
    constexpr int LDA = 40;  // 32 data + 8 pad

    __shared__ alignas(16) u16 aT[128 * LDA];
    __shared__ alignas(16) u16 bT[COUT * LDA];

    const int tid = threadIdx.x;
    const int m0 = blockIdx.x * 128;
    const int n_img = m0 >> 10;
    const int pixbase = m0 & 1023;

    const int r = tid >> 1, half = tid & 1;
    const int pr = pixbase + r;
    const int ohr = pr >> 5, owr = pr & 31;
    const u16* inb = in + (size_t)n_img * Hin * Win * CIN;

    const int wv = tid >> 6, lane = tid & 63;
    const int q = lane >> 4, l16 = lane & 15;
    const int wm = wv / WN, wn = wv % WN;
    const int mbase = wm * (TM * 16), cbase = wn * (TN * 16);

    f32x4 acc[TM][TN] = {};

    for (int t = 0; t < taps.ntaps; ++t) {
        const int ih = ohr * taps.s + taps.dh[t];
        const int iw = owr * taps.s + taps.dw[t];
        const bool ok = ((unsigned)ih < (unsigned)Hin) && ((unsigned)iw < (unsigned)Win);
        const u16* asrc = ok ? (inb + ((size_t)ih * Win + iw) * CIN + half * 16) : inb;
        const u16* bsrc = wT + ((size_t)t * COUT + r) * CIN + half * 16;

        for (int c0 = 0; c0 < CIN; c0 += 32) {
            __syncthreads();
            uint4 a0 = {0,0,0,0}, a1 = {0,0,0,0};
            if (ok) {
                a0 = *(const uint4*)(asrc + c0);
                a1 = *(const uint4*)(asrc + c0 + 8);
            }
            if (RELU_IN) {
                a0.x = relu2(a0.x); a0.y = relu2(a0.y); a0.z = relu2(a0.z); a0.w = relu2(a0.w);
                a1.x = relu2(a1.x); a1.y = relu2(a1.y); a1.z = relu2(a1.z); a1.w = relu2(a1.w);
            }
            *(uint4*)&aT[r * LDA + half * 16]     = a0;
            *(uint4*)&aT[r * LDA + half * 16 + 8] = a1;
            if (COUT == 128 || r < COUT) {
                uint4 b0 = *(const uint4*)(bsrc + c0);
                uint4 b1 = *(const uint4*)(bsrc + c0 + 8);
                *(uint4*)&bT[r * LDA + half * 16]     = b0;
                *(uint4*)&bT[r * LDA + half * 16 + 8] = b1;
            }
            __syncthreads();

            bf16x8 afr[TM], bfr[TN];
            #pragma unroll
            for (int tm = 0; tm < TM; ++tm)
                afr[tm] = *(const bf16x8*)&aT[(mbase + tm*16 + l16) * LDA + q * 8];
            #pragma unroll
            for (int tn = 0; tn < TN; ++tn)
                bfr[tn] = *(const bf16x8*)&bT[(cbase + tn*16 + l16) * LDA + q * 8];
            #pragma unroll
            for (int tm = 0; tm < TM; ++tm)
                #pragma unroll
                for (int tn = 0; tn < TN; ++tn)
                    acc[tm][tn] = __builtin_amdgcn_mfma_f32_16x16x32_bf16(
                        afr[tm], bfr[tn], acc[tm][tn], 0, 0, 0);
        }
    }

    #pragma unroll
    for (int tm = 0; tm < TM; ++tm) {
        #pragma unroll
        for (int tn = 0; tn < TN; ++tn) {
            const int col = cbase + tn*16 + l16;
            const float bv = HAS_BIAS ? bias[col] : 0.0f;
            #pragma unroll
            for (int rg = 0; rg < 4; ++rg) {
                const int m = mbase + tm*16 + q*4 + rg;
                const int pix = pixbase + m;
                const int oh = pix >> 5, ow = pix & 31;
                size_t oidx = (((size_t)n_img * Hout + (oh*OS + OPH)) * Wout
                               + (ow*OS + OPW)) * COUT + col;
                float v = acc[tm][tn][rg] + bv;
                if (RESID) v += bf2f(out[oidx]);
                if (RELU_OUT) v = fmaxf(v, 0.0f);
                out[oidx] = f2bf(v);
            }
        }
    }
}

// ---------------- conv1: 3->64 k4 s2 p1, x NCHW fp32 -> NHWC bf16 ----------------
__global__ void conv1_k(const float* __restrict__ x, const float* __restrict__ wT1,
                        const float* __restrict__ b, u16* __restrict__ out)
{
    int tid = blockIdx.x * 256 + threadIdx.x;
    int co = tid & 63;
    int ow = (tid >> 6) & 63;
    int oh = (tid >> 12) & 63;
    int n  = tid >> 18;
    float acc = b[co];
    #pragma unroll
    for (int kh = 0; kh < 4; ++kh) {
        int ih = oh*2 - 1 + kh;
        if ((unsigned)ih >= 128u) continue;
        #pragma unroll
        for (int kw = 0; kw < 4; ++kw) {
            int iw = ow*2 - 1 + kw;
            if ((unsigned)iw >= 128u) continue;
            #pragma unroll
            for (int ci = 0; ci < 3; ++ci) {
                float xv = x[((size_t)(n*3 + ci) << 14) + ih*128 + iw];
                acc = fmaf(xv, wT1[((ci*4 + kh)*4 + kw)*64 + co], acc);
            }
        }
    }
    out[tid] = f2bf(fmaxf(acc, 0.0f));
}

// ---------------- tc2: ConvT 64->3 k4 s2 p1, NHWC bf16 -> NCHW fp32 ----------------
__global__ void tc2_k(const u16* __restrict__ in, const u16* __restrict__ wT,
                      const float* __restrict__ b, float* __restrict__ out)
{
    int tid = blockIdx.x * 256 + threadIdx.x;
    int ow = tid & 127, oh = (tid >> 7) & 127, n = tid >> 14;
    int poh = oh & 1, pw = ow & 1, oh2 = oh >> 1, ow2 = ow >> 1;
    int pp = poh*2 + pw;
    float a0 = b[0], a1 = b[1], a2 = b[2];
    #pragma unroll
    for (int ta = 0; ta < 2; ++ta) {
        int ih = oh2 + (poh ? (ta ? 0 : 1) : (ta ? -1 : 0));
        if ((unsigned)ih >= 64u) continue;
        #pragma unroll
        for (int tb = 0; tb < 2; ++tb) {
            int iw = ow2 + (pw ? (tb ? 0 : 1) : (tb ? -1 : 0));
            if ((unsigned)iw >= 64u) continue;
            const u16* src = in + (((size_t)n*64 + ih)*64 + iw)*64;
            const u16* wp  = wT + (size_t)((pp*4 + ta*2 + tb)*3)*64;
            for (int d0 = 0; d0 < 64; d0 += 8) {
                uint4 v = *(const uint4*)(src + d0);
                unsigned ua[4] = {v.x, v.y, v.z, v.w};
                #pragma unroll
                for (int j = 0; j < 4; ++j) {
                    float v0 = bf2f((u16)(ua[j] & 0xFFFFu));
                    float v1 = bf2f((u16)(ua[j] >> 16));
                    int d = d0 + 2*j;
                    a0 = fmaf(v0, bf2f(wp[d]),         a0);
                    a0 = fmaf(v1, bf2f(wp[d+1]),       a0);
                    a1 = fmaf(v0, bf2f(wp[64+d]),      a1);
                    a1 = fmaf(v1, bf2f(wp[64+d+1]),    a1);
                    a2 = fmaf(v0, bf2f(wp[128+d]),     a2);
                    a2 = fmaf(v1, bf2f(wp[128+d+1]),   a2);
                }
            }
        }
    }
    size_t ob = (size_t)n*3*16384 + oh*128 + ow;
    out[ob] = a0; out[ob + 16384] = a1; out[ob + 32768] = a2;
}

// ---------------- VQ: E prep ----------------
__global__ void eprep_k(const float* __restrict__ E, u16* __restrict__ Ebf,
                        float* __restrict__ enorm)
{
    int k = blockIdx.x * 256 + threadIdx.x;
    if (k >= 512) return;
    float s = 0.0f;
    #pragma unroll
    for (int d = 0; d < 64; ++d) {
        u16 h = f2bf(E[k*64 + d]);
        Ebf[k*64 + d] = h;
        float v = bf2f(h);
        s = fmaf(v, v, s);
    }
    enorm[k] = s;
}

// ---------------- MFMA vector quantizer (no counts atomics) ----------------
__global__ __launch_bounds__(256)
void vq_mfma_k(const u16* __restrict__ Ze, const u16* __restrict__ Ebf,
               const float* __restrict__ enorm, u16* __restrict__ Zq,
               u16* __restrict__ idx_out, float* __restrict__ sse)
{
    __shared__ int bestk_s[64];
    __shared__ float red[256];
    const int tid = threadIdx.x;
    const int lane = tid & 63, wv = tid >> 6;
    const int q = lane >> 4, l16 = lane & 15;
    const int p0 = blockIdx.x * 64 + wv * 16;

    bf16x8 a0 = *(const bf16x8*)(Ze + (size_t)(p0 + l16) * 64 + q * 8);
    bf16x8 a1 = *(const bf16x8*)(Ze + (size_t)(p0 + l16) * 64 + 32 + q * 8);

    float best[4] = {INFINITY, INFINITY, INFINITY, INFINITY};
    int bk[4] = {0, 0, 0, 0};

    for (int t = 0; t < 32; ++t) {
        const int n = t * 16 + l16;
        bf16x8 b0 = *(const bf16x8*)(Ebf + (size_t)n * 64 + q * 8);
        bf16x8 b1 = *(const bf16x8*)(Ebf + (size_t)n * 64 + 32 + q * 8);
        f32x4 acc = {0.0f, 0.0f, 0.0f, 0.0f};
        acc = __builtin_amdgcn_mfma_f32_16x16x32_bf16(a0, b0, acc, 0, 0, 0);
        acc = __builtin_amdgcn_mfma_f32_16x16x32_bf16(a1, b1, acc, 0, 0, 0);
        const float en = enorm[n];
        #pragma unroll
        for (int rg = 0; rg < 4; ++rg) {
            float sc = en - 2.0f * acc[rg];
            if (sc < best[rg]) { best[rg] = sc; bk[rg] = n; }
        }
    }

    #pragma unroll
    for (int m = 1; m < 16; m <<= 1) {
        #pragma unroll
        for (int rg = 0; rg < 4; ++rg) {
            float os = __shfl_xor(best[rg], m, 64);
            int   ok = __shfl_xor(bk[rg], m, 64);
            if (os < best[rg] || (os == best[rg] && ok < bk[rg])) {
                best[rg] = os; bk[rg] = ok;
            }
        }
    }
    if (l16 == 0) {
        #pragma unroll
        for (int rg = 0; rg < 4; ++rg)
            bestk_s[wv * 16 + q * 4 + rg] = bk[rg];
    }
    __syncthreads();

    const int pos = tid >> 2, seg = tid & 3;
    const int p = blockIdx.x * 64 + pos;
    const int k = bestk_s[pos];
    const u16* ep = Ebf + (size_t)k * 64 + seg * 16;
    const u16* zp = Ze + (size_t)p * 64 + seg * 16;
    u16* qp = Zq + (size_t)p * 64 + seg * 16;
    float local = 0.0f;
    #pragma unroll
    for (int h = 0; h < 2; ++h) {
        uint4 ev = *(const uint4*)(ep + h * 8);
        uint4 zv = *(const uint4*)(zp + h * 8);
        *(uint4*)(qp + h * 8) = ev;
        unsigned ea[4] = {ev.x, ev.y, ev.z, ev.w};
        unsigned za[4] = {zv.x, zv.y, zv.z, zv.w};
        #pragma unroll
        for (int j = 0; j < 4; ++j) {
            float d0 = bf2f((u16)(ea[j] & 0xFFFFu)) - bf2f((u16)(za[j] & 0xFFFFu));
            float d1 = bf2f((u16)(ea[j] >> 16))     - bf2f((u16)(za[j] >> 16));
            local = fmaf(d0, d0, fmaf(d1, d1, local));
        }
    }
    if (seg == 0) idx_out[p] = (u16)k;
    red[tid] = local;
    __syncthreads();
    for (int s = 128; s > 0; s >>= 1) {
        if (tid < s) red[tid] += red[tid + s];
        __syncthreads();
    }
    if (tid == 0) atomicAdd(sse, red[0]);
}

// ---------------- histogram by scan: block k counts code k ----------------
// idx: 65536 u16.  512 blocks x 256 threads; zero atomics, deterministic.
__global__ __launch_bounds__(256)
void hist_k(const u16* __restrict__ idx, float* __restrict__ counts)
{
    __shared__ int red[256];
    const int k = blockIdx.x;
    const int tid = threadIdx.x;
    int c = 0;
    // 65536 u16 = 8192 uint4; thread strides 256
    const uint4* p4 = (const uint4*)idx;
    for (int i = tid; i < 8192; i += 256) {
        uint4 v = p4[i];
        unsigned ua[4] = {v.x, v.y, v.z, v.w};
        #pragma unroll
        for (int j = 0; j < 4; ++j) {
            c += ((ua[j] & 0xFFFFu) == (unsigned)k);
            c += ((ua[j] >> 16)     == (unsigned)k);
        }
    }
    red[tid] = c;
    __syncthreads();
    for (int s = 128; s > 0; s >>= 1) {
        if (tid < s) red[tid] += red[tid + s];
        __syncthreads();
    }
    if (tid == 0) counts[k] = (float)red[0];
}

// ---------------- weight transforms ----------------
__global__ void wconv_tf_k(const float* __restrict__ w, u16* __restrict__ o,
                           int COUT, int CIN, int KK, int total)
{
    int i = blockIdx.x * 256 + threadIdx.x;
    if (i >= total) return;
    int ci = i % CIN; int t = i / CIN; int co = t % COUT; t /= COUT;
    o[i] = f2bf(w[(co*CIN + ci)*KK + t]);
}
__global__ void wtc1_tf_k(const float* __restrict__ w, u16* __restrict__ o)
{
    int i = blockIdx.x * 256 + threadIdx.x;
    if (i >= 131072) return;
    int ci = i & 127; int co = (i >> 7) & 63; int t = (i >> 13) & 3; int p = i >> 15;
    int poh = p >> 1, pw = p & 1; int a = t >> 1, bb = t & 1;
    int kh = poh ? (a ? 2 : 0) : (a ? 3 : 1);
    int kw = pw  ? (bb ? 2 : 0) : (bb ? 3 : 1);
    o[i] = f2bf(w[((ci*64 + co)*4 + kh)*4 + kw]);
}
__global__ void wtc2_tf_k(const float* __restrict__ w, u16* __restrict__ o)
{
    int i = blockIdx.x * 256 + threadIdx.x;
    if (i >= 3072) return;
    int ci = i & 63; int co = (i >> 6) % 3; int t = (i / 192) & 3; int p = i / 768;
    int poh = p >> 1, pw = p & 1; int a = t >> 1, bb = t & 1;
    int kh = poh ? (a ? 2 : 0) : (a ? 3 : 1);
    int kw = pw  ? (bb ? 2 : 0) : (bb ? 3 : 1);
    o[i] = f2bf(w[((ci*3 + co)*4 + kh)*4 + kw]);
}
__global__ void wc1_tf_k(const float* __restrict__ w, float* __restrict__ o)
{
    int i = blockIdx.x * 256 + threadIdx.x;
    if (i >= 3072) return;
    int co = i & 63; int kw = (i >> 6) & 3; int kh = (i >> 8) & 3; int ci = i >> 10;
    o[i] = w[((co*3 + ci)*4 + kh)*4 + kw];
}

// ---------------- scalars ----------------
__global__ void finalize_k(const float* __restrict__ counts, const float* __restrict__ sse,
                           float* __restrict__ out_head, float* __restrict__ out_tail)
{
    __shared__ float red[512];
    int t = threadIdx.x;
    float pr = counts[t] / 65536.0f;
    red[t] = -pr * log2f(pr + 1e-10f);
    __syncthreads();
    for (int s = 256; s > 0; s >>= 1) {
        if (t < s) red[t] += red[t + s];
        __syncthreads();
    }
    if (t == 0) {
        float entropy = red[0];
        float mse = sse[0] / 4194304.0f;
        out_head[0] = 1.25f * mse;
        out_tail[0] = mse;
        out_tail[1] = mse;
        out_tail[2] = exp2f(entropy);
    }
}

__global__ void zero_k(float* __restrict__ p, int n)
{
    int i = blockIdx.x * 256 + threadIdx.x;
    if (i < n) p[i] = 0.0f;
}

// ---------------------------------------------------------------------------
extern "C" void kernel_launch(void* const* d_in, const int* in_sizes, int n_in,
                              void* d_out, int out_size, void* d_ws, size_t ws_size,
                              hipStream_t stream)
{
    const float* x         = (const float*)d_in[0];
    const float* enc_w1    = (const float*)d_in[1];
    const float* enc_b1    = (const float*)d_in[2];
    const float* enc_w2    = (const float*)d_in[3];
    const float* enc_b2    = (const float*)d_in[4];
    const float* enc_w3    = (const float*)d_in[5];
    const float* enc_b3    = (const float*)d_in[6];
    const float* enc_w4    = (const float*)d_in[7];
    const float* enc_b4    = (const float*)d_in[8];
    const float* enc_res_w1= (const float*)d_in[9];
    const float* enc_res_w2= (const float*)d_in[10];
    const float* enc_adj_w = (const float*)d_in[11];
    const float* enc_adj_b = (const float*)d_in[12];
    const float* Ecb       = (const float*)d_in[13];
    const float* dec_adj_w = (const float*)d_in[14];
    const float* dec_adj_b = (const float*)d_in[15];
    const float* dec_res_w1= (const float*)d_in[16];
    const float* dec_res_w2= (const float*)d_in[17];
    const float* tc1_w     = (const float*)d_in[18];
    const float* tc1_b     = (const float*)d_in[19];
    const float* tc2_w     = (const float*)d_in[20];
    const float* tc2_b     = (const float*)d_in[21];

    char* wsb = (char*)d_ws;
    u16*   wc2   = (u16*)(wsb + 0);
    u16*   wc3   = (u16*)(wsb + 262144);
    u16*   wc4   = (u16*)(wsb + 557056);
    u16*   wer1  = (u16*)(wsb + 851968);
    u16*   wer2  = (u16*)(wsb + 1146880);
    u16*   weadj = (u16*)(wsb + 1179648);
    u16*   wdadj = (u16*)(wsb + 1196032);
    u16*   wdr1  = (u16*)(wsb + 1343488);
    u16*   wdr2  = (u16*)(wsb + 1638400);
    u16*   wtc1  = (u16*)(wsb + 1671168);
    u16*   wtc2  = (u16*)(wsb + 1933312);
    float* wc1   = (float*)(wsb + 1939456);
    float* counts= (float*)(wsb + 1951744);
    float* sse   = counts + 512;
    u16*   Ebf   = (u16*)(wsb + 1955840);   // 64 KB
    float* enorm = (float*)(wsb + 2021376); // 2 KB
    u16*   H1    = (u16*)(wsb + 2097152);
    u16*   TR    = (u16*)(wsb + 35651584);
    u16*   H3    = (u16*)(wsb + 52428800);
    u16*   MID   = (u16*)(wsb + 69206016);
    u16*   ZE    = (u16*)(wsb + 77594624);
    u16*   ZQ    = (u16*)(wsb + 85983232);
    u16*   IDX   = (u16*)(wsb + 94371840);  // 128 KB
    u16*   TC1O  = H1;

    float* out  = (float*)d_out;
    float* xrec = out + 1;
    float* tail = out + 1 + 3145728;

    Taps t3x3; t3x3.s = 1; t3x3.ntaps = 9;
    for (int kh = 0; kh < 3; ++kh) for (int kw = 0; kw < 3; ++kw) {
        t3x3.dh[kh*3+kw] = kh - 1; t3x3.dw[kh*3+kw] = kw - 1;
    }
    Taps t1x1; t1x1.s = 1; t1x1.ntaps = 1; t1x1.dh[0] = 0; t1x1.dw[0] = 0;
    Taps t4x4; t4x4.s = 2; t4x4.ntaps = 16;
    for (int kh = 0; kh < 4; ++kh) for (int kw = 0; kw < 4; ++kw) {
        t4x4.dh[kh*4+kw] = kh - 1; t4x4.dw[kh*4+kw] = kw - 1;
    }
    const int dtab[2][2] = {{0, -1}, {1, 0}};
    Taps ttc1[4];
    for (int p = 0; p < 4; ++p) {
        ttc1[p].s = 1; ttc1[p].ntaps = 4;
        for (int a = 0; a < 2; ++a) for (int bb = 0; bb < 2; ++bb) {
            ttc1[p].dh[a*2+bb] = dtab[p>>1][a];
            ttc1[p].dw[a*2+bb] = dtab[p&1][bb];
        }
    }

    // ---- weight transforms + sse zero ----
    zero_k<<<1, 256, 0, stream>>>(sse, 1);
    wc1_tf_k<<<12, 256, 0, stream>>>(enc_w1, wc1);
    wconv_tf_k<<<512, 256, 0, stream>>>(enc_w2, wc2, 128, 64, 16, 131072);
    wconv_tf_k<<<576, 256, 0, stream>>>(enc_w3, wc3, 128, 128, 9, 147456);
    wconv_tf_k<<<576, 256, 0, stream>>>(enc_w4, wc4, 128, 128, 9, 147456);
    for (int i = 0; i < 2; ++i) {
        wconv_tf_k<<<288, 256, 0, stream>>>(enc_res_w1 + i*73728, wer1 + i*73728, 64, 128, 9, 73728);
        wconv_tf_k<<<32,  256, 0, stream>>>(enc_res_w2 + i*8192,  wer2 + i*8192,  128, 64, 1, 8192);
        wconv_tf_k<<<288, 256, 0, stream>>>(dec_res_w1 + i*73728, wdr1 + i*73728, 64, 128, 9, 73728);
        wconv_tf_k<<<32,  256, 0, stream>>>(dec_res_w2 + i*8192,  wdr2 + i*8192,  128, 64, 1, 8192);
    }
    wconv_tf_k<<<32,  256, 0, stream>>>(enc_adj_w, weadj, 64, 128, 1, 8192);
    wconv_tf_k<<<288, 256, 0, stream>>>(dec_adj_w, wdadj, 128, 64, 9, 73728);
    wtc1_tf_k<<<512, 256, 0, stream>>>(tc1_w, wtc1);
    wtc2_tf_k<<<12,  256, 0, stream>>>(tc2_w, wtc2);
    eprep_k<<<2, 256, 0, stream>>>(Ecb, Ebf, enorm);

    // ---- encoder ----
    conv1_k<<<65536, 256, 0, stream>>>(x, wc1, enc_b1, H1);
    mfma_conv_k<64,128,false,true,true,false><<<512, 256, 0, stream>>>
        (H1, wc2, enc_b2, TR, 64, 64, 32, 32, 1, 0, 0, t4x4);
    mfma_conv_k<128,128,false,true,true,false><<<512, 256, 0, stream>>>
        (TR, wc3, enc_b3, H3, 32, 32, 32, 32, 1, 0, 0, t3x3);
    mfma_conv_k<128,128,false,false,true,false><<<512, 256, 0, stream>>>
        (H3, wc4, enc_b4, TR, 32, 32, 32, 32, 1, 0, 0, t3x3);
    for (int i = 0; i < 2; ++i) {
        mfma_conv_k<128,64,true,false,false,false><<<512, 256, 0, stream>>>
            (TR, wer1 + i*73728, nullptr, MID, 32, 32, 32, 32, 1, 0, 0, t3x3);
        mfma_conv_k<64,128,true,false,false,true><<<512, 256, 0, stream>>>
            (MID, wer2 + i*8192, nullptr, TR, 32, 32, 32, 32, 1, 0, 0, t1x1);
    }
    mfma_conv_k<128,64,true,false,true,false><<<512, 256, 0, stream>>>
        (TR, weadj, enc_adj_b, ZE, 32, 32, 32, 32, 1, 0, 0, t1x1);

    // ---- VQ ----
    vq_mfma_k<<<1024, 256, 0, stream>>>(ZE, Ebf, enorm, ZQ, IDX, sse);
    hist_k<<<512, 256, 0, stream>>>(IDX, counts);

    // ---- decoder ----
    mfma_conv_k<64,128,false,false,true,false><<<512, 256, 0, stream>>>
        (ZQ, wdadj, dec_adj_b, H3, 32, 32, 32, 32, 1, 0, 0, t3x3);
    for (int i = 0; i < 2; ++i) {
        mfma_conv_k<128,64,true,false,false,false><<<512, 256, 0, stream>>>
            (H3, wdr1 + i*73728, nullptr, MID, 32, 32, 32, 32, 1, 0, 0, t3x3);
        mfma_conv_k<64,128,true,false,false,true><<<512, 256, 0, stream>>>
            (MID, wdr2 + i*8192, nullptr, H3, 32, 32, 32, 32, 1, 0, 0, t1x1);
    }
    for (int p = 0; p < 4; ++p) {
        mfma_conv_k<128,64,true,true,true,false><<<512, 256, 0, stream>>>
            (H3, wtc1 + p*32768, tc1_b, TC1O, 32, 32, 64, 64, 2, p>>1, p&1, ttc1[p]);
    }
    tc2_k<<<4096, 256, 0, stream>>>(TC1O, wtc2, tc2_b, xrec);

    // ---- scalars ----
    finalize_k<<<1, 512, 0, stream>>>(counts, sse, out, tail);
}

// Round 5
// 762.477 us; speedup vs baseline: 33.6144x; 1.2169x over previous
//
#include <hip/hip_runtime.h>
#include <math.h>

// ---------------------------------------------------------------------------
// VQ-VAE forward: NHWC bf16 trunk, implicit-GEMM MFMA convs (fp32 accum),
// MFMA vector quantizer (no per-position atomics; histogram by scan),
// weight-stationary conv1 (scalar-broadcast weights, all 64 co per thread).
//
// Workspace layout (bytes):
//   [0 .. ~2.0MB)   transformed weights + counts/sse + Ebf + enorm
//   H1  = 2097152   (64,64,64,64)  NHWC bf16  33.5MB   h1, later tc1 out
//   TR  = 35651584  (64,32,32,128) NHWC bf16  16.8MB   enc trunk
//   H3  = 52428800  (64,32,32,128) NHWC bf16  16.8MB   h3, later dec trunk
//   MID = 69206016  (64,32,32,64)  NHWC bf16   8.4MB   res mid
//   ZE  = 77594624  (64,32,32,64)  NHWC bf16   8.4MB
//   ZQ  = 85983232  (64,32,32,64)  NHWC bf16   8.4MB
//   IDX = 94371840  65536 u16      128KB
// ---------------------------------------------------------------------------

typedef unsigned short u16;
typedef __attribute__((ext_vector_type(8))) short bf16x8;
typedef __attribute__((ext_vector_type(4))) float f32x4;

__device__ __forceinline__ float bf2f(u16 h) {
    union { unsigned u; float f; } v; v.u = ((unsigned)h) << 16; return v.f;
}
__device__ __forceinline__ u16 f2bf(float f) {
    union { float f; unsigned u; } v; v.f = f;
    unsigned r = v.u + 0x7FFFu + ((v.u >> 16) & 1u);
    return (u16)(r >> 16);
}
__device__ __forceinline__ unsigned relu2(unsigned x) {
    return x & ~(((x & 0x80008000u) >> 15) * 0xFFFFu);
}

struct Taps { int s; int ntaps; int dh[16]; int dw[16]; };

// ---------------- unified implicit-GEMM MFMA conv ----------------
template<int CIN, int COUT, bool RELU_IN, bool RELU_OUT, bool HAS_BIAS, bool RESID>
__global__ __launch_bounds__(256)
void mfma_conv_k(const u16* __restrict__ in, const u16* __restrict__ wT,
                 const float* __restrict__ bias, u16* __restrict__ out,
                 int Hin, int Win, int Hout, int Wout, int OS, int OPH, int OPW,
                 Taps taps)
{
    constexpr int WN = (COUT == 128) ? 2 : 1;
    constexpr int WM = 4 / WN;
    constexpr int TM = (128 / WM) / 16;
    constexpr int TN = (COUT / WN) / 16;
    constexpr int LDA = 40;  // 32 data + 8 pad

    __shared__ alignas(16) u16 aT[128 * LDA];
    __shared__ alignas(16) u16 bT[COUT * LDA];

    const int tid = threadIdx.x;
    const int m0 = blockIdx.x * 128;
    const int n_img = m0 >> 10;
    const int pixbase = m0 & 1023;

    const int r = tid >> 1, half = tid & 1;
    const int pr = pixbase + r;
    const int ohr = pr >> 5, owr = pr & 31;
    const u16* inb = in + (size_t)n_img * Hin * Win * CIN;

    const int wv = tid >> 6, lane = tid & 63;
    const int q = lane >> 4, l16 = lane & 15;
    const int wm = wv / WN, wn = wv % WN;
    const int mbase = wm * (TM * 16), cbase = wn * (TN * 16);

    f32x4 acc[TM][TN] = {};

    for (int t = 0; t < taps.ntaps; ++t) {
        const int ih = ohr * taps.s + taps.dh[t];
        const int iw = owr * taps.s + taps.dw[t];
        const bool ok = ((unsigned)ih < (unsigned)Hin) && ((unsigned)iw < (unsigned)Win);
        const u16* asrc = ok ? (inb + ((size_t)ih * Win + iw) * CIN + half * 16) : inb;
        const u16* bsrc = wT + ((size_t)t * COUT + r) * CIN + half * 16;

        for (int c0 = 0; c0 < CIN; c0 += 32) {
            __syncthreads();
            uint4 a0 = {0,0,0,0}, a1 = {0,0,0,0};
            if (ok) {
                a0 = *(const uint4*)(asrc + c0);
                a1 = *(const uint4*)(asrc + c0 + 8);
            }
            if (RELU_IN) {
                a0.x = relu2(a0.x); a0.y = relu2(a0.y); a0.z = relu2(a0.z); a0.w = relu2(a0.w);
                a1.x = relu2(a1.x); a1.y = relu2(a1.y); a1.z = relu2(a1.z); a1.w = relu2(a1.w);
            }
            *(uint4*)&aT[r * LDA + half * 16]     = a0;
            *(uint4*)&aT[r * LDA + half * 16 + 8] = a1;
            if (COUT == 128 || r < COUT) {
                uint4 b0 = *(const uint4*)(bsrc + c0);
                uint4 b1 = *(const uint4*)(bsrc + c0 + 8);
                *(uint4*)&bT[r * LDA + half * 16]     = b0;
                *(uint4*)&bT[r * LDA + half * 16 + 8] = b1;
            }
            __syncthreads();

            bf16x8 afr[TM], bfr[TN];
            #pragma unroll
            for (int tm = 0; tm < TM; ++tm)
                afr[tm] = *(const bf16x8*)&aT[(mbase + tm*16 + l16) * LDA + q * 8];
            #pragma unroll
            for (int tn = 0; tn < TN; ++tn)
                bfr[tn] = *(const bf16x8*)&bT[(cbase + tn*16 + l16) * LDA + q * 8];
            #pragma unroll
            for (int tm = 0; tm < TM; ++tm)
                #pragma unroll
                for (int tn = 0; tn < TN; ++tn)
                    acc[tm][tn] = __builtin_amdgcn_mfma_f32_16x16x32_bf16(
                        afr[tm], bfr[tn], acc[tm][tn], 0, 0, 0);
        }
    }

    #pragma unroll
    for (int tm = 0; tm < TM; ++tm) {
        #pragma unroll
        for (int tn = 0; tn < TN; ++tn) {
            const int col = cbase + tn*16 + l16;
            const float bv = HAS_BIAS ? bias[col] : 0.0f;
            #pragma unroll
            for (int rg = 0; rg < 4; ++rg) {
                const int m = mbase + tm*16 + q*4 + rg;
                const int pix = pixbase + m;
                const int oh = pix >> 5, ow = pix & 31;
                size_t oidx = (((size_t)n_img * Hout + (oh*OS + OPH)) * Wout
                               + (ow*OS + OPW)) * COUT + col;
                float v = acc[tm][tn][rg] + bv;
                if (RESID) v += bf2f(out[oidx]);
                if (RELU_OUT) v = fmaxf(v, 0.0f);
                out[oidx] = f2bf(v);
            }
        }
    }
}

// ---------------- conv1: weight-stationary, one pixel/thread, all 64 co ------
// x NCHW fp32; w = enc_w1 OIHW (64,3,4,4) used directly (w[co*48 + ci*16+kh*4+kw],
// wave-uniform index -> scalar loads); out NHWC bf16.
__global__ __launch_bounds__(256)
void conv1_k(const float* __restrict__ x, const float* __restrict__ w,
             const float* __restrict__ b, u16* __restrict__ out)
{
    int tid = blockIdx.x * 256 + threadIdx.x;   // 262144 pixels
    int ow = tid & 63, oh = (tid >> 6) & 63, n = tid >> 12;
    const float* xb = x + (size_t)n * 3 * 16384;
    const int ih0 = oh * 2 - 1, iw0 = ow * 2 - 1;

    float xr[48];
    #pragma unroll
    for (int ci = 0; ci < 3; ++ci) {
        #pragma unroll
        for (int kh = 0; kh < 4; ++kh) {
            int ih = ih0 + kh;
            bool rowok = (unsigned)ih < 128u;
            #pragma unroll
            for (int kw = 0; kw < 4; ++kw) {
                int iw = iw0 + kw;
                bool ok = rowok && ((unsigned)iw < 128u);
                xr[ci*16 + kh*4 + kw] = ok ? xb[ci*16384 + ih*128 + iw] : 0.0f;
            }
        }
    }

    u16* op = out + (size_t)tid * 64;
    #pragma unroll
    for (int cg = 0; cg < 8; ++cg) {
        unsigned pk[4];
        #pragma unroll
        for (int cp = 0; cp < 4; ++cp) {
            const int co = cg*8 + cp*2;
            float a0 = b[co], a1 = b[co + 1];
            const float* w0 = w + co * 48;
            #pragma unroll
            for (int j = 0; j < 48; ++j) {
                a0 = fmaf(xr[j], w0[j],      a0);
                a1 = fmaf(xr[j], w0[48 + j], a1);
            }
            a0 = fmaxf(a0, 0.0f);
            a1 = fmaxf(a1, 0.0f);
            pk[cp] = (unsigned)f2bf(a0) | ((unsigned)f2bf(a1) << 16);
        }
        *(uint4*)(op + cg*8) = *(uint4*)pk;
    }
}

// ---------------- tc2: ConvT 64->3 k4 s2 p1, NHWC bf16 -> NCHW fp32 ----------------
__global__ void tc2_k(const u16* __restrict__ in, const u16* __restrict__ wT,
                      const float* __restrict__ b, float* __restrict__ out)
{
    int tid = blockIdx.x * 256 + threadIdx.x;
    int ow = tid & 127, oh = (tid >> 7) & 127, n = tid >> 14;
    int poh = oh & 1, pw = ow & 1, oh2 = oh >> 1, ow2 = ow >> 1;
    int pp = poh*2 + pw;
    float a0 = b[0], a1 = b[1], a2 = b[2];
    #pragma unroll
    for (int ta = 0; ta < 2; ++ta) {
        int ih = oh2 + (poh ? (ta ? 0 : 1) : (ta ? -1 : 0));
        if ((unsigned)ih >= 64u) continue;
        #pragma unroll
        for (int tb = 0; tb < 2; ++tb) {
            int iw = ow2 + (pw ? (tb ? 0 : 1) : (tb ? -1 : 0));
            if ((unsigned)iw >= 64u) continue;
            const u16* src = in + (((size_t)n*64 + ih)*64 + iw)*64;
            const u16* wp  = wT + (size_t)((pp*4 + ta*2 + tb)*3)*64;
            for (int d0 = 0; d0 < 64; d0 += 8) {
                uint4 v = *(const uint4*)(src + d0);
                unsigned ua[4] = {v.x, v.y, v.z, v.w};
                #pragma unroll
                for (int j = 0; j < 4; ++j) {
                    float v0 = bf2f((u16)(ua[j] & 0xFFFFu));
                    float v1 = bf2f((u16)(ua[j] >> 16));
                    int d = d0 + 2*j;
                    a0 = fmaf(v0, bf2f(wp[d]),         a0);
                    a0 = fmaf(v1, bf2f(wp[d+1]),       a0);
                    a1 = fmaf(v0, bf2f(wp[64+d]),      a1);
                    a1 = fmaf(v1, bf2f(wp[64+d+1]),    a1);
                    a2 = fmaf(v0, bf2f(wp[128+d]),     a2);
                    a2 = fmaf(v1, bf2f(wp[128+d+1]),   a2);
                }
            }
        }
    }
    size_t ob = (size_t)n*3*16384 + oh*128 + ow;
    out[ob] = a0; out[ob + 16384] = a1; out[ob + 32768] = a2;
}

// ---------------- VQ: E prep ----------------
__global__ void eprep_k(const float* __restrict__ E, u16* __restrict__ Ebf,
                        float* __restrict__ enorm)
{
    int k = blockIdx.x * 256 + threadIdx.x;
    if (k >= 512) return;
    float s = 0.0f;
    #pragma unroll
    for (int d = 0; d < 64; ++d) {
        u16 h = f2bf(E[k*64 + d]);
        Ebf[k*64 + d] = h;
        float v = bf2f(h);
        s = fmaf(v, v, s);
    }
    enorm[k] = s;
}

// ---------------- MFMA vector quantizer (no counts atomics) ----------------
__global__ __launch_bounds__(256)
void vq_mfma_k(const u16* __restrict__ Ze, const u16* __restrict__ Ebf,
               const float* __restrict__ enorm, u16* __restrict__ Zq,
               u16* __restrict__ idx_out, float* __restrict__ sse)
{
    __shared__ int bestk_s[64];
    __shared__ float red[256];
    const int tid = threadIdx.x;
    const int lane = tid & 63, wv = tid >> 6;
    const int q = lane >> 4, l16 = lane & 15;
    const int p0 = blockIdx.x * 64 + wv * 16;

    bf16x8 a0 = *(const bf16x8*)(Ze + (size_t)(p0 + l16) * 64 + q * 8);
    bf16x8 a1 = *(const bf16x8*)(Ze + (size_t)(p0 + l16) * 64 + 32 + q * 8);

    float best[4] = {INFINITY, INFINITY, INFINITY, INFINITY};
    int bk[4] = {0, 0, 0, 0};

    for (int t = 0; t < 32; ++t) {
        const int n = t * 16 + l16;
        bf16x8 b0 = *(const bf16x8*)(Ebf + (size_t)n * 64 + q * 8);
        bf16x8 b1 = *(const bf16x8*)(Ebf + (size_t)n * 64 + 32 + q * 8);
        f32x4 acc = {0.0f, 0.0f, 0.0f, 0.0f};
        acc = __builtin_amdgcn_mfma_f32_16x16x32_bf16(a0, b0, acc, 0, 0, 0);
        acc = __builtin_amdgcn_mfma_f32_16x16x32_bf16(a1, b1, acc, 0, 0, 0);
        const float en = enorm[n];
        #pragma unroll
        for (int rg = 0; rg < 4; ++rg) {
            float sc = en - 2.0f * acc[rg];
            if (sc < best[rg]) { best[rg] = sc; bk[rg] = n; }
        }
    }

    #pragma unroll
    for (int m = 1; m < 16; m <<= 1) {
        #pragma unroll
        for (int rg = 0; rg < 4; ++rg) {
            float os = __shfl_xor(best[rg], m, 64);
            int   ok = __shfl_xor(bk[rg], m, 64);
            if (os < best[rg] || (os == best[rg] && ok < bk[rg])) {
                best[rg] = os; bk[rg] = ok;
            }
        }
    }
    if (l16 == 0) {
        #pragma unroll
        for (int rg = 0; rg < 4; ++rg)
            bestk_s[wv * 16 + q * 4 + rg] = bk[rg];
    }
    __syncthreads();

    const int pos = tid >> 2, seg = tid & 3;
    const int p = blockIdx.x * 64 + pos;
    const int k = bestk_s[pos];
    const u16* ep = Ebf + (size_t)k * 64 + seg * 16;
    const u16* zp = Ze + (size_t)p * 64 + seg * 16;
    u16* qp = Zq + (size_t)p * 64 + seg * 16;
    float local = 0.0f;
    #pragma unroll
    for (int h = 0; h < 2; ++h) {
        uint4 ev = *(const uint4*)(ep + h * 8);
        uint4 zv = *(const uint4*)(zp + h * 8);
        *(uint4*)(qp + h * 8) = ev;
        unsigned ea[4] = {ev.x, ev.y, ev.z, ev.w};
        unsigned za[4] = {zv.x, zv.y, zv.z, zv.w};
        #pragma unroll
        for (int j = 0; j < 4; ++j) {
            float d0 = bf2f((u16)(ea[j] & 0xFFFFu)) - bf2f((u16)(za[j] & 0xFFFFu));
            float d1 = bf2f((u16)(ea[j] >> 16))     - bf2f((u16)(za[j] >> 16));
            local = fmaf(d0, d0, fmaf(d1, d1, local));
        }
    }
    if (seg == 0) idx_out[p] = (u16)k;
    red[tid] = local;
    __syncthreads();
    for (int s = 128; s > 0; s >>= 1) {
        if (tid < s) red[tid] += red[tid + s];
        __syncthreads();
    }
    if (tid == 0) atomicAdd(sse, red[0]);
}

// ---------------- histogram by scan: block k counts code k ----------------
__global__ __launch_bounds__(256)
void hist_k(const u16* __restrict__ idx, float* __restrict__ counts)
{
    __shared__ int red[256];
    const int k = blockIdx.x;
    const int tid = threadIdx.x;
    int c = 0;
    const uint4* p4 = (const uint4*)idx;
    for (int i = tid; i < 8192; i += 256) {
        uint4 v = p4[i];
        unsigned ua[4] = {v.x, v.y, v.z, v.w};
        #pragma unroll
        for (int j = 0; j < 4; ++j) {
            c += ((ua[j] & 0xFFFFu) == (unsigned)k);
            c += ((ua[j] >> 16)     == (unsigned)k);
        }
    }
    red[tid] = c;
    __syncthreads();
    for (int s = 128; s > 0; s >>= 1) {
        if (tid < s) red[tid] += red[tid + s];
        __syncthreads();
    }
    if (tid == 0) counts[k] = (float)red[0];
}

// ---------------- weight transforms ----------------
__global__ void wconv_tf_k(const float* __restrict__ w, u16* __restrict__ o,
                           int COUT, int CIN, int KK, int total)
{
    int i = blockIdx.x * 256 + threadIdx.x;
    if (i >= total) return;
    int ci = i % CIN; int t = i / CIN; int co = t % COUT; t /= COUT;
    o[i] = f2bf(w[(co*CIN + ci)*KK + t]);
}
__global__ void wtc1_tf_k(const float* __restrict__ w, u16* __restrict__ o)
{
    int i = blockIdx.x * 256 + threadIdx.x;
    if (i >= 131072) return;
    int ci = i & 127; int co = (i >> 7) & 63; int t = (i >> 13) & 3; int p = i >> 15;
    int poh = p >> 1, pw = p & 1; int a = t >> 1, bb = t & 1;
    int kh = poh ? (a ? 2 : 0) : (a ? 3 : 1);
    int kw = pw  ? (bb ? 2 : 0) : (bb ? 3 : 1);
    o[i] = f2bf(w[((ci*64 + co)*4 + kh)*4 + kw]);
}
__global__ void wtc2_tf_k(const float* __restrict__ w, u16* __restrict__ o)
{
    int i = blockIdx.x * 256 + threadIdx.x;
    if (i >= 3072) return;
    int ci = i & 63; int co = (i >> 6) % 3; int t = (i / 192) & 3; int p = i / 768;
    int poh = p >> 1, pw = p & 1; int a = t >> 1, bb = t & 1;
    int kh = poh ? (a ? 2 : 0) : (a ? 3 : 1);
    int kw = pw  ? (bb ? 2 : 0) : (bb ? 3 : 1);
    o[i] = f2bf(w[((ci*3 + co)*4 + kh)*4 + kw]);
}

// ---------------- scalars ----------------
__global__ void finalize_k(const float* __restrict__ counts, const float* __restrict__ sse,
                           float* __restrict__ out_head, float* __restrict__ out_tail)
{
    __shared__ float red[512];
    int t = threadIdx.x;
    float pr = counts[t] / 65536.0f;
    red[t] = -pr * log2f(pr + 1e-10f);
    __syncthreads();
    for (int s = 256; s > 0; s >>= 1) {
        if (t < s) red[t] += red[t + s];
        __syncthreads();
    }
    if (t == 0) {
        float entropy = red[0];
        float mse = sse[0] / 4194304.0f;
        out_head[0] = 1.25f * mse;
        out_tail[0] = mse;
        out_tail[1] = mse;
        out_tail[2] = exp2f(entropy);
    }
}

__global__ void zero_k(float* __restrict__ p, int n)
{
    int i = blockIdx.x * 256 + threadIdx.x;
    if (i < n) p[i] = 0.0f;
}

// ---------------------------------------------------------------------------
extern "C" void kernel_launch(void* const* d_in, const int* in_sizes, int n_in,
                              void* d_out, int out_size, void* d_ws, size_t ws_size,
                              hipStream_t stream)
{
    const float* x         = (const float*)d_in[0];
    const float* enc_w1    = (const float*)d_in[1];
    const float* enc_b1    = (const float*)d_in[2];
    const float* enc_w2    = (const float*)d_in[3];
    const float* enc_b2    = (const float*)d_in[4];
    const float* enc_w3    = (const float*)d_in[5];
    const float* enc_b3    = (const float*)d_in[6];
    const float* enc_w4    = (const float*)d_in[7];
    const float* enc_b4    = (const float*)d_in[8];
    const float* enc_res_w1= (const float*)d_in[9];
    const float* enc_res_w2= (const float*)d_in[10];
    const float* enc_adj_w = (const float*)d_in[11];
    const float* enc_adj_b = (const float*)d_in[12];
    const float* Ecb       = (const float*)d_in[13];
    const float* dec_adj_w = (const float*)d_in[14];
    const float* dec_adj_b = (const float*)d_in[15];
    const float* dec_res_w1= (const float*)d_in[16];
    const float* dec_res_w2= (const float*)d_in[17];
    const float* tc1_w     = (const float*)d_in[18];
    const float* tc1_b     = (const float*)d_in[19];
    const float* tc2_w     = (const float*)d_in[20];
    const float* tc2_b     = (const float*)d_in[21];

    char* wsb = (char*)d_ws;
    u16*   wc2   = (u16*)(wsb + 0);
    u16*   wc3   = (u16*)(wsb + 262144);
    u16*   wc4   = (u16*)(wsb + 557056);
    u16*   wer1  = (u16*)(wsb + 851968);
    u16*   wer2  = (u16*)(wsb + 1146880);
    u16*   weadj = (u16*)(wsb + 1179648);
    u16*   wdadj = (u16*)(wsb + 1196032);
    u16*   wdr1  = (u16*)(wsb + 1343488);
    u16*   wdr2  = (u16*)(wsb + 1638400);
    u16*   wtc1  = (u16*)(wsb + 1671168);
    u16*   wtc2  = (u16*)(wsb + 1933312);
    float* counts= (float*)(wsb + 1951744);
    float* sse   = counts + 512;
    u16*   Ebf   = (u16*)(wsb + 1955840);   // 64 KB
    float* enorm = (float*)(wsb + 2021376); // 2 KB
    u16*   H1    = (u16*)(wsb + 2097152);
    u16*   TR    = (u16*)(wsb + 35651584);
    u16*   H3    = (u16*)(wsb + 52428800);
    u16*   MID   = (u16*)(wsb + 69206016);
    u16*   ZE    = (u16*)(wsb + 77594624);
    u16*   ZQ    = (u16*)(wsb + 85983232);
    u16*   IDX   = (u16*)(wsb + 94371840);  // 128 KB
    u16*   TC1O  = H1;

    float* out  = (float*)d_out;
    float* xrec = out + 1;
    float* tail = out + 1 + 3145728;

    Taps t3x3; t3x3.s = 1; t3x3.ntaps = 9;
    for (int kh = 0; kh < 3; ++kh) for (int kw = 0; kw < 3; ++kw) {
        t3x3.dh[kh*3+kw] = kh - 1; t3x3.dw[kh*3+kw] = kw - 1;
    }
    Taps t1x1; t1x1.s = 1; t1x1.ntaps = 1; t1x1.dh[0] = 0; t1x1.dw[0] = 0;
    Taps t4x4; t4x4.s = 2; t4x4.ntaps = 16;
    for (int kh = 0; kh < 4; ++kh) for (int kw = 0; kw < 4; ++kw) {
        t4x4.dh[kh*4+kw] = kh - 1; t4x4.dw[kh*4+kw] = kw - 1;
    }
    const int dtab[2][2] = {{0, -1}, {1, 0}};
    Taps ttc1[4];
    for (int p = 0; p < 4; ++p) {
        ttc1[p].s = 1; ttc1[p].ntaps = 4;
        for (int a = 0; a < 2; ++a) for (int bb = 0; bb < 2; ++bb) {
            ttc1[p].dh[a*2+bb] = dtab[p>>1][a];
            ttc1[p].dw[a*2+bb] = dtab[p&1][bb];
        }
    }

    // ---- weight transforms + sse zero ----
    zero_k<<<1, 256, 0, stream>>>(sse, 1);
    wconv_tf_k<<<512, 256, 0, stream>>>(enc_w2, wc2, 128, 64, 16, 131072);
    wconv_tf_k<<<576, 256, 0, stream>>>(enc_w3, wc3, 128, 128, 9, 147456);
    wconv_tf_k<<<576, 256, 0, stream>>>(enc_w4, wc4, 128, 128, 9, 147456);
    for (int i = 0; i < 2; ++i) {
        wconv_tf_k<<<288, 256, 0, stream>>>(enc_res_w1 + i*73728, wer1 + i*73728, 64, 128, 9, 73728);
        wconv_tf_k<<<32,  256, 0, stream>>>(enc_res_w2 + i*8192,  wer2 + i*8192,  128, 64, 1, 8192);
        wconv_tf_k<<<288, 256, 0, stream>>>(dec_res_w1 + i*73728, wdr1 + i*73728, 64, 128, 9, 73728);
        wconv_tf_k<<<32,  256, 0, stream>>>(dec_res_w2 + i*8192,  wdr2 + i*8192,  128, 64, 1, 8192);
    }
    wconv_tf_k<<<32,  256, 0, stream>>>(enc_adj_w, weadj, 64, 128, 1, 8192);
    wconv_tf_k<<<288, 256, 0, stream>>>(dec_adj_w, wdadj, 128, 64, 9, 73728);
    wtc1_tf_k<<<512, 256, 0, stream>>>(tc1_w, wtc1);
    wtc2_tf_k<<<12,  256, 0, stream>>>(tc2_w, wtc2);
    eprep_k<<<2, 256, 0, stream>>>(Ecb, Ebf, enorm);

    // ---- encoder ----
    conv1_k<<<1024, 256, 0, stream>>>(x, enc_w1, enc_b1, H1);
    mfma_conv_k<64,128,false,true,true,false><<<512, 256, 0, stream>>>
        (H1, wc2, enc_b2, TR, 64, 64, 32, 32, 1, 0, 0, t4x4);
    mfma_conv_k<128,128,false,true,true,false><<<512, 256, 0, stream>>>
        (TR, wc3, enc_b3, H3, 32, 32, 32, 32, 1, 0, 0, t3x3);
    mfma_conv_k<128,128,false,false,true,false><<<512, 256, 0, stream>>>
        (H3, wc4, enc_b4, TR, 32, 32, 32, 32, 1, 0, 0, t3x3);
    for (int i = 0; i < 2; ++i) {
        mfma_conv_k<128,64,true,false,false,false><<<512, 256, 0, stream>>>
            (TR, wer1 + i*73728, nullptr, MID, 32, 32, 32, 32, 1, 0, 0, t3x3);
        mfma_conv_k<64,128,true,false,false,true><<<512, 256, 0, stream>>>
            (MID, wer2 + i*8192, nullptr, TR, 32, 32, 32, 32, 1, 0, 0, t1x1);
    }
    mfma_conv_k<128,64,true,false,true,false><<<512, 256, 0, stream>>>
        (TR, weadj, enc_adj_b, ZE, 32, 32, 32, 32, 1, 0, 0, t1x1);

    // ---- VQ ----
    vq_mfma_k<<<1024, 256, 0, stream>>>(ZE, Ebf, enorm, ZQ, IDX, sse);
    hist_k<<<512, 256, 0, stream>>>(IDX, counts);

    // ---- decoder ----
    mfma_conv_k<64,128,false,false,true,false><<<512, 256, 0, stream>>>
        (ZQ, wdadj, dec_adj_b, H3, 32, 32, 32, 32, 1, 0, 0, t3x3);
    for (int i = 0; i < 2; ++i) {
        mfma_conv_k<128,64,true,false,false,false><<<512, 256, 0, stream>>>
            (H3, wdr1 + i*73728, nullptr, MID, 32, 32, 32, 32, 1, 0, 0, t3x3);
        mfma_conv_k<64,128,true,false,false,true><<<512, 256, 0, stream>>>
            (MID, wdr2 + i*8192, nullptr, H3, 32, 32, 32, 32, 1, 0, 0, t1x1);
    }
    for (int p = 0; p < 4; ++p) {
        mfma_conv_k<128,64,true,true,true,false><<<512, 256, 0, stream>>>
            (H3, wtc1 + p*32768, tc1_b, TC1O, 32, 32, 64, 64, 2, p>>1, p&1, ttc1[p]);
    }
    tc2_k<<<4096, 256, 0, stream>>>(TC1O, wtc2, tc2_b, xrec);

    // ---- scalars ----
    finalize_k<<<1, 512, 0, stream>>>(counts, sse, out, tail);
}

// Round 6
// 668.483 us; speedup vs baseline: 38.3409x; 1.1406x over previous
//
#include <hip/hip_runtime.h>
#include <math.h>

// ---------------------------------------------------------------------------
// VQ-VAE forward: NHWC bf16 trunk, implicit-GEMM MFMA convs (fp32 accum),
// MFMA vector quantizer, MFMA tc2 (zero-padded parity GEMM, LDS-transposed
// NCHW epilogue), weight-stationary conv1.
//
// Workspace layout (bytes):
//   [0 .. ~2.0MB)   transformed weights + counts/sse + Ebf + enorm
//   H1  = 2097152   (64,64,64,64)  NHWC bf16  33.5MB   h1, later tc1 out
//   TR  = 35651584  (64,32,32,128) NHWC bf16  16.8MB   enc trunk
//   H3  = 52428800  (64,32,32,128) NHWC bf16  16.8MB   h3, later dec trunk
//   MID = 69206016  (64,32,32,64)  NHWC bf16   8.4MB   res mid
//   ZE  = 77594624  (64,32,32,64)  NHWC bf16   8.4MB
//   ZQ  = 85983232  (64,32,32,64)  NHWC bf16   8.4MB
//   IDX = 94371840  65536 u16      128KB
// ---------------------------------------------------------------------------

typedef unsigned short u16;
typedef __attribute__((ext_vector_type(8))) short bf16x8;
typedef __attribute__((ext_vector_type(4))) float f32x4;

__device__ __forceinline__ float bf2f(u16 h) {
    union { unsigned u; float f; } v; v.u = ((unsigned)h) << 16; return v.f;
}
__device__ __forceinline__ u16 f2bf(float f) {
    union { float f; unsigned u; } v; v.f = f;
    unsigned r = v.u + 0x7FFFu + ((v.u >> 16) & 1u);
    return (u16)(r >> 16);
}
__device__ __forceinline__ unsigned relu2(unsigned x) {
    return x & ~(((x & 0x80008000u) >> 15) * 0xFFFFu);
}

struct Taps { int s; int ntaps; int dh[16]; int dw[16]; };

// ---------------- unified implicit-GEMM MFMA conv ----------------
template<int CIN, int COUT, bool RELU_IN, bool RELU_OUT, bool HAS_BIAS, bool RESID>
__global__ __launch_bounds__(256)
void mfma_conv_k(const u16* __restrict__ in, const u16* __restrict__ wT,
                 const float* __restrict__ bias, u16* __restrict__ out,
                 int Hin, int Win, int Hout, int Wout, int OS, int OPH, int OPW,
                 Taps taps)
{
    constexpr int WN = (COUT == 128) ? 2 : 1;
    constexpr int WM = 4 / WN;
    constexpr int TM = (128 / WM) / 16;
    constexpr int TN = (COUT / WN) / 16;
    constexpr int LDA = 40;  // 32 data + 8 pad

    __shared__ alignas(16) u16 aT[128 * LDA];
    __shared__ alignas(16) u16 bT[COUT * LDA];

    const int tid = threadIdx.x;
    const int m0 = blockIdx.x * 128;
    const int n_img = m0 >> 10;
    const int pixbase = m0 & 1023;

    const int r = tid >> 1, half = tid & 1;
    const int pr = pixbase + r;
    const int ohr = pr >> 5, owr = pr & 31;
    const u16* inb = in + (size_t)n_img * Hin * Win * CIN;

    const int wv = tid >> 6, lane = tid & 63;
    const int q = lane >> 4, l16 = lane & 15;
    const int wm = wv / WN, wn = wv % WN;
    const int mbase = wm * (TM * 16), cbase = wn * (TN * 16);

    f32x4 acc[TM][TN] = {};

    for (int t = 0; t < taps.ntaps; ++t) {
        const int ih = ohr * taps.s + taps.dh[t];
        const int iw = owr * taps.s + taps.dw[t];
        const bool ok = ((unsigned)ih < (unsigned)Hin) && ((unsigned)iw < (unsigned)Win);
        const u16* asrc = ok ? (inb + ((size_t)ih * Win + iw) * CIN + half * 16) : inb;
        const u16* bsrc = wT + ((size_t)t * COUT + r) * CIN + half * 16;

        for (int c0 = 0; c0 < CIN; c0 += 32) {
            __syncthreads();
            uint4 a0 = {0,0,0,0}, a1 = {0,0,0,0};
            if (ok) {
                a0 = *(const uint4*)(asrc + c0);
                a1 = *(const uint4*)(asrc + c0 + 8);
            }
            if (RELU_IN) {
                a0.x = relu2(a0.x); a0.y = relu2(a0.y); a0.z = relu2(a0.z); a0.w = relu2(a0.w);
                a1.x = relu2(a1.x); a1.y = relu2(a1.y); a1.z = relu2(a1.z); a1.w = relu2(a1.w);
            }
            *(uint4*)&aT[r * LDA + half * 16]     = a0;
            *(uint4*)&aT[r * LDA + half * 16 + 8] = a1;
            if (COUT == 128 || r < COUT) {
                uint4 b0 = *(const uint4*)(bsrc + c0);
                uint4 b1 = *(const uint4*)(bsrc + c0 + 8);
                *(uint4*)&bT[r * LDA + half * 16]     = b0;
                *(uint4*)&bT[r * LDA + half * 16 + 8] = b1;
            }
            __syncthreads();

            bf16x8 afr[TM], bfr[TN];
            #pragma unroll
            for (int tm = 0; tm < TM; ++tm)
                afr[tm] = *(const bf16x8*)&aT[(mbase + tm*16 + l16) * LDA + q * 8];
            #pragma unroll
            for (int tn = 0; tn < TN; ++tn)
                bfr[tn] = *(const bf16x8*)&bT[(cbase + tn*16 + l16) * LDA + q * 8];
            #pragma unroll
            for (int tm = 0; tm < TM; ++tm)
                #pragma unroll
                for (int tn = 0; tn < TN; ++tn)
                    acc[tm][tn] = __builtin_amdgcn_mfma_f32_16x16x32_bf16(
                        afr[tm], bfr[tn], acc[tm][tn], 0, 0, 0);
        }
    }

    #pragma unroll
    for (int tm = 0; tm < TM; ++tm) {
        #pragma unroll
        for (int tn = 0; tn < TN; ++tn) {
            const int col = cbase + tn*16 + l16;
            const float bv = HAS_BIAS ? bias[col] : 0.0f;
            #pragma unroll
            for (int rg = 0; rg < 4; ++rg) {
                const int m = mbase + tm*16 + q*4 + rg;
                const int pix = pixbase + m;
                const int oh = pix >> 5, ow = pix & 31;
                size_t oidx = (((size_t)n_img * Hout + (oh*OS + OPH)) * Wout
                               + (ow*OS + OPW)) * COUT + col;
                float v = acc[tm][tn][rg] + bv;
                if (RESID) v += bf2f(out[oidx]);
                if (RELU_OUT) v = fmaxf(v, 0.0f);
                out[oidx] = f2bf(v);
            }
        }
    }
}

// ---------------- conv1: weight-stationary, one pixel/thread, all 64 co ------
__global__ __launch_bounds__(256)
void conv1_k(const float* __restrict__ x, const float* __restrict__ w,
             const float* __restrict__ b, u16* __restrict__ out)
{
    int tid = blockIdx.x * 256 + threadIdx.x;   // 262144 pixels
    int ow = tid & 63, oh = (tid >> 6) & 63, n = tid >> 12;
    const float* xb = x + (size_t)n * 3 * 16384;
    const int ih0 = oh * 2 - 1, iw0 = ow * 2 - 1;

    float xr[48];
    #pragma unroll
    for (int ci = 0; ci < 3; ++ci) {
        #pragma unroll
        for (int kh = 0; kh < 4; ++kh) {
            int ih = ih0 + kh;
            bool rowok = (unsigned)ih < 128u;
            #pragma unroll
            for (int kw = 0; kw < 4; ++kw) {
                int iw = iw0 + kw;
                bool ok = rowok && ((unsigned)iw < 128u);
                xr[ci*16 + kh*4 + kw] = ok ? xb[ci*16384 + ih*128 + iw] : 0.0f;
            }
        }
    }

    u16* op = out + (size_t)tid * 64;
    #pragma unroll
    for (int cg = 0; cg < 8; ++cg) {
        unsigned pk[4];
        #pragma unroll
        for (int cp = 0; cp < 4; ++cp) {
            const int co = cg*8 + cp*2;
            float a0 = b[co], a1 = b[co + 1];
            const float* w0 = w + co * 48;
            #pragma unroll
            for (int j = 0; j < 48; ++j) {
                a0 = fmaf(xr[j], w0[j],      a0);
                a1 = fmaf(xr[j], w0[48 + j], a1);
            }
            a0 = fmaxf(a0, 0.0f);
            a1 = fmaxf(a1, 0.0f);
            pk[cp] = (unsigned)f2bf(a0) | ((unsigned)f2bf(a1) << 16);
        }
        *(uint4*)(op + cg*8) = *(uint4*)pk;
    }
}

// ---------------- tc2 as MFMA parity GEMM ----------------
// in: TC1O NHWC bf16 (64,64,64,64).  wT: bf16 [tap 9][col 16][ci 64], zero-
// padded per parity.  out: NCHW fp32 (64,3,128,128).  col = pp*4+co (co<3).
__global__ __launch_bounds__(256)
void tc2_mfma_k(const u16* __restrict__ in, const u16* __restrict__ wT,
                const float* __restrict__ bias, float* __restrict__ out)
{
    constexpr int LDA = 40;
    __shared__ alignas(16) u16 aT[128 * LDA];
    __shared__ alignas(16) u16 bT[16 * LDA];
    __shared__ float cT[128 * 17];

    const int tid = threadIdx.x;
    const int m0 = blockIdx.x * 128;          // 2048 blocks, 32/image
    const int n_img = m0 >> 12;
    const int pixbase = m0 & 4095;            // multiple of 128 -> 2 y-rows
    const int y0 = pixbase >> 6;

    const int r = tid >> 1, half = tid & 1;
    const int pr = pixbase + r;
    const int yr = pr >> 6, xr = pr & 63;
    const u16* inb = in + (size_t)n_img * 4096 * 64;

    const int wv = tid >> 6, lane = tid & 63;
    const int q = lane >> 4, l16 = lane & 15;
    const int mbase = wv * 32;

    f32x4 acc[2] = {};

    for (int t = 0; t < 9; ++t) {
        const int ih = yr + t/3 - 1;
        const int iw = xr + t%3 - 1;
        const bool ok = ((unsigned)ih < 64u) && ((unsigned)iw < 64u);
        const u16* asrc = ok ? (inb + ((size_t)ih * 64 + iw) * 64 + half * 16) : inb;
        const u16* bsrc = wT + ((size_t)t * 16 + r) * 64 + half * 16;

        for (int c0 = 0; c0 < 64; c0 += 32) {
            __syncthreads();
            uint4 a0 = {0,0,0,0}, a1 = {0,0,0,0};
            if (ok) {
                a0 = *(const uint4*)(asrc + c0);
                a1 = *(const uint4*)(asrc + c0 + 8);
            }
            *(uint4*)&aT[r * LDA + half * 16]     = a0;
            *(uint4*)&aT[r * LDA + half * 16 + 8] = a1;
            if (r < 16) {
                *(uint4*)&bT[r * LDA + half * 16]     = *(const uint4*)(bsrc + c0);
                *(uint4*)&bT[r * LDA + half * 16 + 8] = *(const uint4*)(bsrc + c0 + 8);
            }
            __syncthreads();

            bf16x8 af0 = *(const bf16x8*)&aT[(mbase + l16) * LDA + q * 8];
            bf16x8 af1 = *(const bf16x8*)&aT[(mbase + 16 + l16) * LDA + q * 8];
            bf16x8 bf  = *(const bf16x8*)&bT[l16 * LDA + q * 8];
            acc[0] = __builtin_amdgcn_mfma_f32_16x16x32_bf16(af0, bf, acc[0], 0, 0, 0);
            acc[1] = __builtin_amdgcn_mfma_f32_16x16x32_bf16(af1, bf, acc[1], 0, 0, 0);
        }
    }

    // accumulators -> LDS (col=lane&15, row=(lane>>4)*4+reg)
    #pragma unroll
    for (int tm = 0; tm < 2; ++tm)
        #pragma unroll
        for (int rg = 0; rg < 4; ++rg)
            cT[(mbase + tm*16 + q*4 + rg) * 17 + l16] = acc[tm][rg];
    __syncthreads();

    // coalesced NCHW store: 4 oh-rows x 128 ow x 3 co = 1536 floats
    #pragma unroll
    for (int it = 0; it < 6; ++it) {
        int j = it * 256 + tid;
        int co  = j >> 9;
        int rem = j & 511;
        int ohl = rem >> 7;
        int ow  = rem & 127;
        int oh  = 2*y0 + ohl;
        int lp  = (ohl >> 1) * 64 + (ow >> 1);
        int col = ((ohl & 1) * 2 + (ow & 1)) * 4 + co;
        float v = cT[lp * 17 + col] + bias[co];
        out[(((size_t)n_img * 3 + co) * 128 + oh) * 128 + ow] = v;
    }
}

// ---------------- VQ: E prep ----------------
__global__ void eprep_k(const float* __restrict__ E, u16* __restrict__ Ebf,
                        float* __restrict__ enorm)
{
    int k = blockIdx.x * 256 + threadIdx.x;
    if (k >= 512) return;
    float s = 0.0f;
    #pragma unroll
    for (int d = 0; d < 64; ++d) {
        u16 h = f2bf(E[k*64 + d]);
        Ebf[k*64 + d] = h;
        float v = bf2f(h);
        s = fmaf(v, v, s);
    }
    enorm[k] = s;
}

// ---------------- MFMA vector quantizer (no counts atomics) ----------------
__global__ __launch_bounds__(256)
void vq_mfma_k(const u16* __restrict__ Ze, const u16* __restrict__ Ebf,
               const float* __restrict__ enorm, u16* __restrict__ Zq,
               u16* __restrict__ idx_out, float* __restrict__ sse)
{
    __shared__ int bestk_s[64];
    __shared__ float red[256];
    const int tid = threadIdx.x;
    const int lane = tid & 63, wv = tid >> 6;
    const int q = lane >> 4, l16 = lane & 15;
    const int p0 = blockIdx.x * 64 + wv * 16;

    bf16x8 a0 = *(const bf16x8*)(Ze + (size_t)(p0 + l16) * 64 + q * 8);
    bf16x8 a1 = *(const bf16x8*)(Ze + (size_t)(p0 + l16) * 64 + 32 + q * 8);

    float best[4] = {INFINITY, INFINITY, INFINITY, INFINITY};
    int bk[4] = {0, 0, 0, 0};

    for (int t = 0; t < 32; ++t) {
        const int n = t * 16 + l16;
        bf16x8 b0 = *(const bf16x8*)(Ebf + (size_t)n * 64 + q * 8);
        bf16x8 b1 = *(const bf16x8*)(Ebf + (size_t)n * 64 + 32 + q * 8);
        f32x4 acc = {0.0f, 0.0f, 0.0f, 0.0f};
        acc = __builtin_amdgcn_mfma_f32_16x16x32_bf16(a0, b0, acc, 0, 0, 0);
        acc = __builtin_amdgcn_mfma_f32_16x16x32_bf16(a1, b1, acc, 0, 0, 0);
        const float en = enorm[n];
        #pragma unroll
        for (int rg = 0; rg < 4; ++rg) {
            float sc = en - 2.0f * acc[rg];
            if (sc < best[rg]) { best[rg] = sc; bk[rg] = n; }
        }
    }

    #pragma unroll
    for (int m = 1; m < 16; m <<= 1) {
        #pragma unroll
        for (int rg = 0; rg < 4; ++rg) {
            float os = __shfl_xor(best[rg], m, 64);
            int   ok = __shfl_xor(bk[rg], m, 64);
            if (os < best[rg] || (os == best[rg] && ok < bk[rg])) {
                best[rg] = os; bk[rg] = ok;
            }
        }
    }
    if (l16 == 0) {
        #pragma unroll
        for (int rg = 0; rg < 4; ++rg)
            bestk_s[wv * 16 + q * 4 + rg] = bk[rg];
    }
    __syncthreads();

    const int pos = tid >> 2, seg = tid & 3;
    const int p = blockIdx.x * 64 + pos;
    const int k = bestk_s[pos];
    const u16* ep = Ebf + (size_t)k * 64 + seg * 16;
    const u16* zp = Ze + (size_t)p * 64 + seg * 16;
    u16* qp = Zq + (size_t)p * 64 + seg * 16;
    float local = 0.0f;
    #pragma unroll
    for (int h = 0; h < 2; ++h) {
        uint4 ev = *(const uint4*)(ep + h * 8);
        uint4 zv = *(const uint4*)(zp + h * 8);
        *(uint4*)(qp + h * 8) = ev;
        unsigned ea[4] = {ev.x, ev.y, ev.z, ev.w};
        unsigned za[4] = {zv.x, zv.y, zv.z, zv.w};
        #pragma unroll
        for (int j = 0; j < 4; ++j) {
            float d0 = bf2f((u16)(ea[j] & 0xFFFFu)) - bf2f((u16)(za[j] & 0xFFFFu));
            float d1 = bf2f((u16)(ea[j] >> 16))     - bf2f((u16)(za[j] >> 16));
            local = fmaf(d0, d0, fmaf(d1, d1, local));
        }
    }
    if (seg == 0) idx_out[p] = (u16)k;
    red[tid] = local;
    __syncthreads();
    for (int s = 128; s > 0; s >>= 1) {
        if (tid < s) red[tid] += red[tid + s];
        __syncthreads();
    }
    if (tid == 0) atomicAdd(sse, red[0]);
}

// ---------------- histogram by scan: block k counts code k ----------------
__global__ __launch_bounds__(256)
void hist_k(const u16* __restrict__ idx, float* __restrict__ counts)
{
    __shared__ int red[256];
    const int k = blockIdx.x;
    const int tid = threadIdx.x;
    int c = 0;
    const uint4* p4 = (const uint4*)idx;
    for (int i = tid; i < 8192; i += 256) {
        uint4 v = p4[i];
        unsigned ua[4] = {v.x, v.y, v.z, v.w};
        #pragma unroll
        for (int j = 0; j < 4; ++j) {
            c += ((ua[j] & 0xFFFFu) == (unsigned)k);
            c += ((ua[j] >> 16)     == (unsigned)k);
        }
    }
    red[tid] = c;
    __syncthreads();
    for (int s = 128; s > 0; s >>= 1) {
        if (tid < s) red[tid] += red[tid + s];
        __syncthreads();
    }
    if (tid == 0) counts[k] = (float)red[0];
}

// ---------------- weight transforms ----------------
__global__ void wconv_tf_k(const float* __restrict__ w, u16* __restrict__ o,
                           int COUT, int CIN, int KK, int total)
{
    int i = blockIdx.x * 256 + threadIdx.x;
    if (i >= total) return;
    int ci = i % CIN; int t = i / CIN; int co = t % COUT; t /= COUT;
    o[i] = f2bf(w[(co*CIN + ci)*KK + t]);
}
__global__ void wtc1_tf_k(const float* __restrict__ w, u16* __restrict__ o)
{
    int i = blockIdx.x * 256 + threadIdx.x;
    if (i >= 131072) return;
    int ci = i & 127; int co = (i >> 7) & 63; int t = (i >> 13) & 3; int p = i >> 15;
    int poh = p >> 1, pw = p & 1; int a = t >> 1, bb = t & 1;
    int kh = poh ? (a ? 2 : 0) : (a ? 3 : 1);
    int kw = pw  ? (bb ? 2 : 0) : (bb ? 3 : 1);
    o[i] = f2bf(w[((ci*64 + co)*4 + kh)*4 + kw]);
}
// tc2 zero-padded parity GEMM weights: [tap 9][col 16][ci 64]
// w layout (Cin=64, Cout=3, 4, 4): w[((ci*3 + co)*4 + kh)*4 + kw]
__global__ void wtc2b_tf_k(const float* __restrict__ w, u16* __restrict__ o)
{
    int i = blockIdx.x * 256 + threadIdx.x;   // 9216
    if (i >= 9216) return;
    int ci = i & 63; int col = (i >> 6) & 15; int t = i >> 10;
    int dh = t / 3 - 1, dw = t % 3 - 1;
    int pp = col >> 2, co = col & 3;
    float v = 0.0f;
    if (co < 3) {
        int poh = pp >> 1, pw = pp & 1;
        int kh = poh ? (dh == 1 ? 0 : (dh == 0 ? 2 : -1))
                     : (dh == 0 ? 1 : (dh == -1 ? 3 : -1));
        int kw = pw  ? (dw == 1 ? 0 : (dw == 0 ? 2 : -1))
                     : (dw == 0 ? 1 : (dw == -1 ? 3 : -1));
        if (kh >= 0 && kw >= 0)
            v = w[((ci*3 + co)*4 + kh)*4 + kw];
    }
    o[i] = f2bf(v);
}

// ---------------- scalars ----------------
__global__ void finalize_k(const float* __restrict__ counts, const float* __restrict__ sse,
                           float* __restrict__ out_head, float* __restrict__ out_tail)
{
    __shared__ float red[512];
    int t = threadIdx.x;
    float pr = counts[t] / 65536.0f;
    red[t] = -pr * log2f(pr + 1e-10f);
    __syncthreads();
    for (int s = 256; s > 0; s >>= 1) {
        if (t < s) red[t] += red[t + s];
        __syncthreads();
    }
    if (t == 0) {
        float entropy = red[0];
        float mse = sse[0] / 4194304.0f;
        out_head[0] = 1.25f * mse;
        out_tail[0] = mse;
        out_tail[1] = mse;
        out_tail[2] = exp2f(entropy);
    }
}

__global__ void zero_k(float* __restrict__ p, int n)
{
    int i = blockIdx.x * 256 + threadIdx.x;
    if (i < n) p[i] = 0.0f;
}

// ---------------------------------------------------------------------------
extern "C" void kernel_launch(void* const* d_in, const int* in_sizes, int n_in,
                              void* d_out, int out_size, void* d_ws, size_t ws_size,
                              hipStream_t stream)
{
    const float* x         = (const float*)d_in[0];
    const float* enc_w1    = (const float*)d_in[1];
    const float* enc_b1    = (const float*)d_in[2];
    const float* enc_w2    = (const float*)d_in[3];
    const float* enc_b2    = (const float*)d_in[4];
    const float* enc_w3    = (const float*)d_in[5];
    const float* enc_b3    = (const float*)d_in[6];
    const float* enc_w4    = (const float*)d_in[7];
    const float* enc_b4    = (const float*)d_in[8];
    const float* enc_res_w1= (const float*)d_in[9];
    const float* enc_res_w2= (const float*)d_in[10];
    const float* enc_adj_w = (const float*)d_in[11];
    const float* enc_adj_b = (const float*)d_in[12];
    const float* Ecb       = (const float*)d_in[13];
    const float* dec_adj_w = (const float*)d_in[14];
    const float* dec_adj_b = (const float*)d_in[15];
    const float* dec_res_w1= (const float*)d_in[16];
    const float* dec_res_w2= (const float*)d_in[17];
    const float* tc1_w     = (const float*)d_in[18];
    const float* tc1_b     = (const float*)d_in[19];
    const float* tc2_w     = (const float*)d_in[20];
    const float* tc2_b     = (const float*)d_in[21];

    char* wsb = (char*)d_ws;
    u16*   wc2   = (u16*)(wsb + 0);
    u16*   wc3   = (u16*)(wsb + 262144);
    u16*   wc4   = (u16*)(wsb + 557056);
    u16*   wer1  = (u16*)(wsb + 851968);
    u16*   wer2  = (u16*)(wsb + 1146880);
    u16*   weadj = (u16*)(wsb + 1179648);
    u16*   wdadj = (u16*)(wsb + 1196032);
    u16*   wdr1  = (u16*)(wsb + 1343488);
    u16*   wdr2  = (u16*)(wsb + 1638400);
    u16*   wtc1  = (u16*)(wsb + 1671168);
    u16*   wtc2b = (u16*)(wsb + 1933312);   // 18432 B, ends at 1951744
    float* counts= (float*)(wsb + 1951744);
    float* sse   = counts + 512;
    u16*   Ebf   = (u16*)(wsb + 1955840);   // 64 KB
    float* enorm = (float*)(wsb + 2021376); // 2 KB
    u16*   H1    = (u16*)(wsb + 2097152);
    u16*   TR    = (u16*)(wsb + 35651584);
    u16*   H3    = (u16*)(wsb + 52428800);
    u16*   MID   = (u16*)(wsb + 69206016);
    u16*   ZE    = (u16*)(wsb + 77594624);
    u16*   ZQ    = (u16*)(wsb + 85983232);
    u16*   IDX   = (u16*)(wsb + 94371840);  // 128 KB
    u16*   TC1O  = H1;

    float* out  = (float*)d_out;
    float* xrec = out + 1;
    float* tail = out + 1 + 3145728;

    Taps t3x3; t3x3.s = 1; t3x3.ntaps = 9;
    for (int kh = 0; kh < 3; ++kh) for (int kw = 0; kw < 3; ++kw) {
        t3x3.dh[kh*3+kw] = kh - 1; t3x3.dw[kh*3+kw] = kw - 1;
    }
    Taps t1x1; t1x1.s = 1; t1x1.ntaps = 1; t1x1.dh[0] = 0; t1x1.dw[0] = 0;
    Taps t4x4; t4x4.s = 2; t4x4.ntaps = 16;
    for (int kh = 0; kh < 4; ++kh) for (int kw = 0; kw < 4; ++kw) {
        t4x4.dh[kh*4+kw] = kh - 1; t4x4.dw[kh*4+kw] = kw - 1;
    }
    const int dtab[2][2] = {{0, -1}, {1, 0}};
    Taps ttc1[4];
    for (int p = 0; p < 4; ++p) {
        ttc1[p].s = 1; ttc1[p].ntaps = 4;
        for (int a = 0; a < 2; ++a) for (int bb = 0; bb < 2; ++bb) {
            ttc1[p].dh[a*2+bb] = dtab[p>>1][a];
            ttc1[p].dw[a*2+bb] = dtab[p&1][bb];
        }
    }

    // ---- weight transforms + sse zero ----
    zero_k<<<1, 256, 0, stream>>>(sse, 1);
    wconv_tf_k<<<512, 256, 0, stream>>>(enc_w2, wc2, 128, 64, 16, 131072);
    wconv_tf_k<<<576, 256, 0, stream>>>(enc_w3, wc3, 128, 128, 9, 147456);
    wconv_tf_k<<<576, 256, 0, stream>>>(enc_w4, wc4, 128, 128, 9, 147456);
    for (int i = 0; i < 2; ++i) {
        wconv_tf_k<<<288, 256, 0, stream>>>(enc_res_w1 + i*73728, wer1 + i*73728, 64, 128, 9, 73728);
        wconv_tf_k<<<32,  256, 0, stream>>>(enc_res_w2 + i*8192,  wer2 + i*8192,  128, 64, 1, 8192);
        wconv_tf_k<<<288, 256, 0, stream>>>(dec_res_w1 + i*73728, wdr1 + i*73728, 64, 128, 9, 73728);
        wconv_tf_k<<<32,  256, 0, stream>>>(dec_res_w2 + i*8192,  wdr2 + i*8192,  128, 64, 1, 8192);
    }
    wconv_tf_k<<<32,  256, 0, stream>>>(enc_adj_w, weadj, 64, 128, 1, 8192);
    wconv_tf_k<<<288, 256, 0, stream>>>(dec_adj_w, wdadj, 128, 64, 9, 73728);
    wtc1_tf_k<<<512, 256, 0, stream>>>(tc1_w, wtc1);
    wtc2b_tf_k<<<36, 256, 0, stream>>>(tc2_w, wtc2b);
    eprep_k<<<2, 256, 0, stream>>>(Ecb, Ebf, enorm);

    // ---- encoder ----
    conv1_k<<<1024, 256, 0, stream>>>(x, enc_w1, enc_b1, H1);
    mfma_conv_k<64,128,false,true,true,false><<<512, 256, 0, stream>>>
        (H1, wc2, enc_b2, TR, 64, 64, 32, 32, 1, 0, 0, t4x4);
    mfma_conv_k<128,128,false,true,true,false><<<512, 256, 0, stream>>>
        (TR, wc3, enc_b3, H3, 32, 32, 32, 32, 1, 0, 0, t3x3);
    mfma_conv_k<128,128,false,false,true,false><<<512, 256, 0, stream>>>
        (H3, wc4, enc_b4, TR, 32, 32, 32, 32, 1, 0, 0, t3x3);
    for (int i = 0; i < 2; ++i) {
        mfma_conv_k<128,64,true,false,false,false><<<512, 256, 0, stream>>>
            (TR, wer1 + i*73728, nullptr, MID, 32, 32, 32, 32, 1, 0, 0, t3x3);
        mfma_conv_k<64,128,true,false,false,true><<<512, 256, 0, stream>>>
            (MID, wer2 + i*8192, nullptr, TR, 32, 32, 32, 32, 1, 0, 0, t1x1);
    }
    mfma_conv_k<128,64,true,false,true,false><<<512, 256, 0, stream>>>
        (TR, weadj, enc_adj_b, ZE, 32, 32, 32, 32, 1, 0, 0, t1x1);

    // ---- VQ ----
    vq_mfma_k<<<1024, 256, 0, stream>>>(ZE, Ebf, enorm, ZQ, IDX, sse);
    hist_k<<<512, 256, 0, stream>>>(IDX, counts);

    // ---- decoder ----
    mfma_conv_k<64,128,false,false,true,false><<<512, 256, 0, stream>>>
        (ZQ, wdadj, dec_adj_b, H3, 32, 32, 32, 32, 1, 0, 0, t3x3);
    for (int i = 0; i < 2; ++i) {
        mfma_conv_k<128,64,true,false,false,false><<<512, 256, 0, stream>>>
            (H3, wdr1 + i*73728, nullptr, MID, 32, 32, 32, 32, 1, 0, 0, t3x3);
        mfma_conv_k<64,128,true,false,false,true><<<512, 256, 0, stream>>>
            (MID, wdr2 + i*8192, nullptr, H3, 32, 32, 32, 32, 1, 0, 0, t1x1);
    }
    for (int p = 0; p < 4; ++p) {
        mfma_conv_k<128,64,true,true,true,false><<<512, 256, 0, stream>>>
            (H3, wtc1 + p*32768, tc1_b, TC1O, 32, 32, 64, 64, 2, p>>1, p&1, ttc1[p]);
    }
    tc2_mfma_k<<<2048, 256, 0, stream>>>(TC1O, wtc2b, tc2_b, xrec);

    // ---- scalars ----
    finalize_k<<<1, 512, 0, stream>>>(counts, sse, out, tail);
}

// Round 7
// 640.720 us; speedup vs baseline: 40.0022x; 1.0433x over previous
//
#include <hip/hip_runtime.h>
#include <math.h>

// ---------------------------------------------------------------------------
// VQ-VAE forward: NHWC bf16 trunk, implicit-GEMM MFMA convs (fp32 accum),
// MFMA vector quantizer, MFMA tc2, weight-stationary conv1 with LDS-coalesced
// stores (fixes 4.7x HBM write amplification seen in r6 counters).
//
// Workspace layout (bytes):
//   [0 .. ~2.0MB)   transformed weights + counts/sse + Ebf + enorm
//   H1  = 2097152   (64,64,64,64)  NHWC bf16  33.5MB   h1, later tc1 out
//   TR  = 35651584  (64,32,32,128) NHWC bf16  16.8MB   enc trunk
//   H3  = 52428800  (64,32,32,128) NHWC bf16  16.8MB   h3, later dec trunk
//   MID = 69206016  (64,32,32,64)  NHWC bf16   8.4MB   res mid
//   ZE  = 77594624  (64,32,32,64)  NHWC bf16   8.4MB
//   ZQ  = 85983232  (64,32,32,64)  NHWC bf16   8.4MB
//   IDX = 94371840  65536 u16      128KB
// ---------------------------------------------------------------------------

typedef unsigned short u16;
typedef __attribute__((ext_vector_type(8))) short bf16x8;
typedef __attribute__((ext_vector_type(4))) float f32x4;

__device__ __forceinline__ float bf2f(u16 h) {
    union { unsigned u; float f; } v; v.u = ((unsigned)h) << 16; return v.f;
}
__device__ __forceinline__ u16 f2bf(float f) {
    union { float f; unsigned u; } v; v.f = f;
    unsigned r = v.u + 0x7FFFu + ((v.u >> 16) & 1u);
    return (u16)(r >> 16);
}
__device__ __forceinline__ unsigned relu2(unsigned x) {
    return x & ~(((x & 0x80008000u) >> 15) * 0xFFFFu);
}

struct Taps { int s; int ntaps; int dh[16]; int dw[16]; };

// ---------------- unified implicit-GEMM MFMA conv ----------------
template<int CIN, int COUT, bool RELU_IN, bool RELU_OUT, bool HAS_BIAS, bool RESID>
__global__ __launch_bounds__(256)
void mfma_conv_k(const u16* __restrict__ in, const u16* __restrict__ wT,
                 const float* __restrict__ bias, u16* __restrict__ out,
                 int Hin, int Win, int Hout, int Wout, int OS, int OPH, int OPW,
                 Taps taps)
{
    constexpr int WN = (COUT == 128) ? 2 : 1;
    constexpr int WM = 4 / WN;
    constexpr int TM = (128 / WM) / 16;
    constexpr int TN = (COUT / WN) / 16;
    constexpr int LDA = 40;  // 32 data + 8 pad

    __shared__ alignas(16) u16 aT[128 * LDA];
    __shared__ alignas(16) u16 bT[COUT * LDA];

    const int tid = threadIdx.x;
    const int m0 = blockIdx.x * 128;
    const int n_img = m0 >> 10;
    const int pixbase = m0 & 1023;

    const int r = tid >> 1, half = tid & 1;
    const int pr = pixbase + r;
    const int ohr = pr >> 5, owr = pr & 31;
    const u16* inb = in + (size_t)n_img * Hin * Win * CIN;

    const int wv = tid >> 6, lane = tid & 63;
    const int q = lane >> 4, l16 = lane & 15;
    const int wm = wv / WN, wn = wv % WN;
    const int mbase = wm * (TM * 16), cbase = wn * (TN * 16);

    f32x4 acc[TM][TN] = {};

    for (int t = 0; t < taps.ntaps; ++t) {
        const int ih = ohr * taps.s + taps.dh[t];
        const int iw = owr * taps.s + taps.dw[t];
        const bool ok = ((unsigned)ih < (unsigned)Hin) && ((unsigned)iw < (unsigned)Win);
        const u16* asrc = ok ? (inb + ((size_t)ih * Win + iw) * CIN + half * 16) : inb;
        const u16* bsrc = wT + ((size_t)t * COUT + r) * CIN + half * 16;

        for (int c0 = 0; c0 < CIN; c0 += 32) {
            __syncthreads();
            uint4 a0 = {0,0,0,0}, a1 = {0,0,0,0};
            if (ok) {
                a0 = *(const uint4*)(asrc + c0);
                a1 = *(const uint4*)(asrc + c0 + 8);
            }
            if (RELU_IN) {
                a0.x = relu2(a0.x); a0.y = relu2(a0.y); a0.z = relu2(a0.z); a0.w = relu2(a0.w);
                a1.x = relu2(a1.x); a1.y = relu2(a1.y); a1.z = relu2(a1.z); a1.w = relu2(a1.w);
            }
            *(uint4*)&aT[r * LDA + half * 16]     = a0;
            *(uint4*)&aT[r * LDA + half * 16 + 8] = a1;
            if (COUT == 128 || r < COUT) {
                uint4 b0 = *(const uint4*)(bsrc + c0);
                uint4 b1 = *(const uint4*)(bsrc + c0 + 8);
                *(uint4*)&bT[r * LDA + half * 16]     = b0;
                *(uint4*)&bT[r * LDA + half * 16 + 8] = b1;
            }
            __syncthreads();

            bf16x8 afr[TM], bfr[TN];
            #pragma unroll
            for (int tm = 0; tm < TM; ++tm)
                afr[tm] = *(const bf16x8*)&aT[(mbase + tm*16 + l16) * LDA + q * 8];
            #pragma unroll
            for (int tn = 0; tn < TN; ++tn)
                bfr[tn] = *(const bf16x8*)&bT[(cbase + tn*16 + l16) * LDA + q * 8];
            #pragma unroll
            for (int tm = 0; tm < TM; ++tm)
                #pragma unroll
                for (int tn = 0; tn < TN; ++tn)
                    acc[tm][tn] = __builtin_amdgcn_mfma_f32_16x16x32_bf16(
                        afr[tm], bfr[tn], acc[tm][tn], 0, 0, 0);
        }
    }

    #pragma unroll
    for (int tm = 0; tm < TM; ++tm) {
        #pragma unroll
        for (int tn = 0; tn < TN; ++tn) {
            const int col = cbase + tn*16 + l16;
            const float bv = HAS_BIAS ? bias[col] : 0.0f;
            #pragma unroll
            for (int rg = 0; rg < 4; ++rg) {
                const int m = mbase + tm*16 + q*4 + rg;
                const int pix = pixbase + m;
                const int oh = pix >> 5, ow = pix & 31;
                size_t oidx = (((size_t)n_img * Hout + (oh*OS + OPH)) * Wout
                               + (ow*OS + OPW)) * COUT + col;
                float v = acc[tm][tn][rg] + bv;
                if (RESID) v += bf2f(out[oidx]);
                if (RELU_OUT) v = fmaxf(v, 0.0f);
                out[oidx] = f2bf(v);
            }
        }
    }
}

// ---------------- conv1: weight-stationary + LDS-coalesced stores ------------
// x NCHW fp32; w = enc_w1 OIHW (64,3,4,4) direct (wave-uniform -> s_load);
// out NHWC bf16.  Epilogue: LDS round-trip so each wave store instruction
// writes 4KB contiguous (fixes partial-sector HBM write amplification).
__global__ __launch_bounds__(256)
void conv1_k(const float* __restrict__ x, const float* __restrict__ w,
             const float* __restrict__ b, u16* __restrict__ out)
{
    constexpr int LDC = 72;   // u16 row stride (64 data + 8 pad)
    __shared__ alignas(16) u16 cbuf[256 * LDC];

    int tid = threadIdx.x;
    int gpix = blockIdx.x * 256 + tid;   // 262144 pixels
    int ow = gpix & 63, oh = (gpix >> 6) & 63, n = gpix >> 12;
    const float* xb = x + (size_t)n * 3 * 16384;
    const int ih0 = oh * 2 - 1, iw0 = ow * 2 - 1;

    float xr[48];
    #pragma unroll
    for (int ci = 0; ci < 3; ++ci) {
        #pragma unroll
        for (int kh = 0; kh < 4; ++kh) {
            int ih = ih0 + kh;
            bool rowok = (unsigned)ih < 128u;
            #pragma unroll
            for (int kw = 0; kw < 4; ++kw) {
                int iw = iw0 + kw;
                bool ok = rowok && ((unsigned)iw < 128u);
                xr[ci*16 + kh*4 + kw] = ok ? xb[ci*16384 + ih*128 + iw] : 0.0f;
            }
        }
    }

    #pragma unroll
    for (int cg = 0; cg < 8; ++cg) {
        unsigned pk[4];
        #pragma unroll
        for (int cp = 0; cp < 4; ++cp) {
            const int co = cg*8 + cp*2;
            float a0 = b[co], a1 = b[co + 1];
            const float* w0 = w + co * 48;
            #pragma unroll
            for (int j = 0; j < 48; ++j) {
                a0 = fmaf(xr[j], w0[j],      a0);
                a1 = fmaf(xr[j], w0[48 + j], a1);
            }
            a0 = fmaxf(a0, 0.0f);
            a1 = fmaxf(a1, 0.0f);
            pk[cp] = (unsigned)f2bf(a0) | ((unsigned)f2bf(a1) << 16);
        }
        *(uint4*)&cbuf[tid * LDC + cg * 8] = *(uint4*)pk;
    }
    __syncthreads();

    // coalesced stores: 2048 uint4s, lane-consecutive -> address-consecutive
    u16* ob = out + (size_t)blockIdx.x * 256 * 64;
    #pragma unroll
    for (int it = 0; it < 8; ++it) {
        int j = it * 256 + tid;               // uint4 index in block output
        uint4 v = *(const uint4*)&cbuf[(j >> 3) * LDC + (j & 7) * 8];
        *(uint4*)(ob + j * 8) = v;
    }
}

// ---------------- tc2 as MFMA parity GEMM ----------------
__global__ __launch_bounds__(256)
void tc2_mfma_k(const u16* __restrict__ in, const u16* __restrict__ wT,
                const float* __restrict__ bias, float* __restrict__ out)
{
    constexpr int LDA = 40;
    __shared__ alignas(16) u16 aT[128 * LDA];
    __shared__ alignas(16) u16 bT[16 * LDA];
    __shared__ float cT[128 * 17];

    const int tid = threadIdx.x;
    const int m0 = blockIdx.x * 128;
    const int n_img = m0 >> 12;
    const int pixbase = m0 & 4095;
    const int y0 = pixbase >> 6;

    const int r = tid >> 1, half = tid & 1;
    const int pr = pixbase + r;
    const int yr = pr >> 6, xr = pr & 63;
    const u16* inb = in + (size_t)n_img * 4096 * 64;

    const int wv = tid >> 6, lane = tid & 63;
    const int q = lane >> 4, l16 = lane & 15;
    const int mbase = wv * 32;

    f32x4 acc[2] = {};

    for (int t = 0; t < 9; ++t) {
        const int ih = yr + t/3 - 1;
        const int iw = xr + t%3 - 1;
        const bool ok = ((unsigned)ih < 64u) && ((unsigned)iw < 64u);
        const u16* asrc = ok ? (inb + ((size_t)ih * 64 + iw) * 64 + half * 16) : inb;
        const u16* bsrc = wT + ((size_t)t * 16 + r) * 64 + half * 16;

        for (int c0 = 0; c0 < 64; c0 += 32) {
            __syncthreads();
            uint4 a0 = {0,0,0,0}, a1 = {0,0,0,0};
            if (ok) {
                a0 = *(const uint4*)(asrc + c0);
                a1 = *(const uint4*)(asrc + c0 + 8);
            }
            *(uint4*)&aT[r * LDA + half * 16]     = a0;
            *(uint4*)&aT[r * LDA + half * 16 + 8] = a1;
            if (r < 16) {
                *(uint4*)&bT[r * LDA + half * 16]     = *(const uint4*)(bsrc + c0);
                *(uint4*)&bT[r * LDA + half * 16 + 8] = *(const uint4*)(bsrc + c0 + 8);
            }
            __syncthreads();

            bf16x8 af0 = *(const bf16x8*)&aT[(mbase + l16) * LDA + q * 8];
            bf16x8 af1 = *(const bf16x8*)&aT[(mbase + 16 + l16) * LDA + q * 8];
            bf16x8 bf  = *(const bf16x8*)&bT[l16 * LDA + q * 8];
            acc[0] = __builtin_amdgcn_mfma_f32_16x16x32_bf16(af0, bf, acc[0], 0, 0, 0);
            acc[1] = __builtin_amdgcn_mfma_f32_16x16x32_bf16(af1, bf, acc[1], 0, 0, 0);
        }
    }

    #pragma unroll
    for (int tm = 0; tm < 2; ++tm)
        #pragma unroll
        for (int rg = 0; rg < 4; ++rg)
            cT[(mbase + tm*16 + q*4 + rg) * 17 + l16] = acc[tm][rg];
    __syncthreads();

    #pragma unroll
    for (int it = 0; it < 6; ++it) {
        int j = it * 256 + tid;
        int co  = j >> 9;
        int rem = j & 511;
        int ohl = rem >> 7;
        int ow  = rem & 127;
        int oh  = 2*y0 + ohl;
        int lp  = (ohl >> 1) * 64 + (ow >> 1);
        int col = ((ohl & 1) * 2 + (ow & 1)) * 4 + co;
        float v = cT[lp * 17 + col] + bias[co];
        out[(((size_t)n_img * 3 + co) * 128 + oh) * 128 + ow] = v;
    }
}

// ---------------- VQ: E prep ----------------
__global__ void eprep_k(const float* __restrict__ E, u16* __restrict__ Ebf,
                        float* __restrict__ enorm)
{
    int k = blockIdx.x * 256 + threadIdx.x;
    if (k >= 512) return;
    float s = 0.0f;
    #pragma unroll
    for (int d = 0; d < 64; ++d) {
        u16 h = f2bf(E[k*64 + d]);
        Ebf[k*64 + d] = h;
        float v = bf2f(h);
        s = fmaf(v, v, s);
    }
    enorm[k] = s;
}

// ---------------- MFMA vector quantizer (no counts atomics) ----------------
__global__ __launch_bounds__(256)
void vq_mfma_k(const u16* __restrict__ Ze, const u16* __restrict__ Ebf,
               const float* __restrict__ enorm, u16* __restrict__ Zq,
               u16* __restrict__ idx_out, float* __restrict__ sse)
{
    __shared__ int bestk_s[64];
    __shared__ float red[256];
    const int tid = threadIdx.x;
    const int lane = tid & 63, wv = tid >> 6;
    const int q = lane >> 4, l16 = lane & 15;
    const int p0 = blockIdx.x * 64 + wv * 16;

    bf16x8 a0 = *(const bf16x8*)(Ze + (size_t)(p0 + l16) * 64 + q * 8);
    bf16x8 a1 = *(const bf16x8*)(Ze + (size_t)(p0 + l16) * 64 + 32 + q * 8);

    float best[4] = {INFINITY, INFINITY, INFINITY, INFINITY};
    int bk[4] = {0, 0, 0, 0};

    for (int t = 0; t < 32; ++t) {
        const int n = t * 16 + l16;
        bf16x8 b0 = *(const bf16x8*)(Ebf + (size_t)n * 64 + q * 8);
        bf16x8 b1 = *(const bf16x8*)(Ebf + (size_t)n * 64 + 32 + q * 8);
        f32x4 acc = {0.0f, 0.0f, 0.0f, 0.0f};
        acc = __builtin_amdgcn_mfma_f32_16x16x32_bf16(a0, b0, acc, 0, 0, 0);
        acc = __builtin_amdgcn_mfma_f32_16x16x32_bf16(a1, b1, acc, 0, 0, 0);
        const float en = enorm[n];
        #pragma unroll
        for (int rg = 0; rg < 4; ++rg) {
            float sc = en - 2.0f * acc[rg];
            if (sc < best[rg]) { best[rg] = sc; bk[rg] = n; }
        }
    }

    #pragma unroll
    for (int m = 1; m < 16; m <<= 1) {
        #pragma unroll
        for (int rg = 0; rg < 4; ++rg) {
            float os = __shfl_xor(best[rg], m, 64);
            int   ok = __shfl_xor(bk[rg], m, 64);
            if (os < best[rg] || (os == best[rg] && ok < bk[rg])) {
                best[rg] = os; bk[rg] = ok;
            }
        }
    }
    if (l16 == 0) {
        #pragma unroll
        for (int rg = 0; rg < 4; ++rg)
            bestk_s[wv * 16 + q * 4 + rg] = bk[rg];
    }
    __syncthreads();

    const int pos = tid >> 2, seg = tid & 3;
    const int p = blockIdx.x * 64 + pos;
    const int k = bestk_s[pos];
    const u16* ep = Ebf + (size_t)k * 64 + seg * 16;
    const u16* zp = Ze + (size_t)p * 64 + seg * 16;
    u16* qp = Zq + (size_t)p * 64 + seg * 16;
    float local = 0.0f;
    #pragma unroll
    for (int h = 0; h < 2; ++h) {
        uint4 ev = *(const uint4*)(ep + h * 8);
        uint4 zv = *(const uint4*)(zp + h * 8);
        *(uint4*)(qp + h * 8) = ev;
        unsigned ea[4] = {ev.x, ev.y, ev.z, ev.w};
        unsigned za[4] = {zv.x, zv.y, zv.z, zv.w};
        #pragma unroll
        for (int j = 0; j < 4; ++j) {
            float d0 = bf2f((u16)(ea[j] & 0xFFFFu)) - bf2f((u16)(za[j] & 0xFFFFu));
            float d1 = bf2f((u16)(ea[j] >> 16))     - bf2f((u16)(za[j] >> 16));
            local = fmaf(d0, d0, fmaf(d1, d1, local));
        }
    }
    if (seg == 0) idx_out[p] = (u16)k;
    red[tid] = local;
    __syncthreads();
    for (int s = 128; s > 0; s >>= 1) {
        if (tid < s) red[tid] += red[tid + s];
        __syncthreads();
    }
    if (tid == 0) atomicAdd(sse, red[0]);
}

// ---------------- histogram by scan: block k counts code k ----------------
__global__ __launch_bounds__(256)
void hist_k(const u16* __restrict__ idx, float* __restrict__ counts)
{
    __shared__ int red[256];
    const int k = blockIdx.x;
    const int tid = threadIdx.x;
    int c = 0;
    const uint4* p4 = (const uint4*)idx;
    for (int i = tid; i < 8192; i += 256) {
        uint4 v = p4[i];
        unsigned ua[4] = {v.x, v.y, v.z, v.w};
        #pragma unroll
        for (int j = 0; j < 4; ++j) {
            c += ((ua[j] & 0xFFFFu) == (unsigned)k);
            c += ((ua[j] >> 16)     == (unsigned)k);
        }
    }
    red[tid] = c;
    __syncthreads();
    for (int s = 128; s > 0; s >>= 1) {
        if (tid < s) red[tid] += red[tid + s];
        __syncthreads();
    }
    if (tid == 0) counts[k] = (float)red[0];
}

// ---------------- weight transforms ----------------
__global__ void wconv_tf_k(const float* __restrict__ w, u16* __restrict__ o,
                           int COUT, int CIN, int KK, int total)
{
    int i = blockIdx.x * 256 + threadIdx.x;
    if (i >= total) return;
    int ci = i % CIN; int t = i / CIN; int co = t % COUT; t /= COUT;
    o[i] = f2bf(w[(co*CIN + ci)*KK + t]);
}
__global__ void wtc1_tf_k(const float* __restrict__ w, u16* __restrict__ o)
{
    int i = blockIdx.x * 256 + threadIdx.x;
    if (i >= 131072) return;
    int ci = i & 127; int co = (i >> 7) & 63; int t = (i >> 13) & 3; int p = i >> 15;
    int poh = p >> 1, pw = p & 1; int a = t >> 1, bb = t & 1;
    int kh = poh ? (a ? 2 : 0) : (a ? 3 : 1);
    int kw = pw  ? (bb ? 2 : 0) : (bb ? 3 : 1);
    o[i] = f2bf(w[((ci*64 + co)*4 + kh)*4 + kw]);
}
// tc2 zero-padded parity GEMM weights: [tap 9][col 16][ci 64]
__global__ void wtc2b_tf_k(const float* __restrict__ w, u16* __restrict__ o)
{
    int i = blockIdx.x * 256 + threadIdx.x;   // 9216
    if (i >= 9216) return;
    int ci = i & 63; int col = (i >> 6) & 15; int t = i >> 10;
    int dh = t / 3 - 1, dw = t % 3 - 1;
    int pp = col >> 2, co = col & 3;
    float v = 0.0f;
    if (co < 3) {
        int poh = pp >> 1, pw = pp & 1;
        int kh = poh ? (dh == 1 ? 0 : (dh == 0 ? 2 : -1))
                     : (dh == 0 ? 1 : (dh == -1 ? 3 : -1));
        int kw = pw  ? (dw == 1 ? 0 : (dw == 0 ? 2 : -1))
                     : (dw == 0 ? 1 : (dw == -1 ? 3 : -1));
        if (kh >= 0 && kw >= 0)
            v = w[((ci*3 + co)*4 + kh)*4 + kw];
    }
    o[i] = f2bf(v);
}

// ---------------- scalars ----------------
__global__ void finalize_k(const float* __restrict__ counts, const float* __restrict__ sse,
                           float* __restrict__ out_head, float* __restrict__ out_tail)
{
    __shared__ float red[512];
    int t = threadIdx.x;
    float pr = counts[t] / 65536.0f;
    red[t] = -pr * log2f(pr + 1e-10f);
    __syncthreads();
    for (int s = 256; s > 0; s >>= 1) {
        if (t < s) red[t] += red[t + s];
        __syncthreads();
    }
    if (t == 0) {
        float entropy = red[0];
        float mse = sse[0] / 4194304.0f;
        out_head[0] = 1.25f * mse;
        out_tail[0] = mse;
        out_tail[1] = mse;
        out_tail[2] = exp2f(entropy);
    }
}

__global__ void zero_k(float* __restrict__ p, int n)
{
    int i = blockIdx.x * 256 + threadIdx.x;
    if (i < n) p[i] = 0.0f;
}

// ---------------------------------------------------------------------------
extern "C" void kernel_launch(void* const* d_in, const int* in_sizes, int n_in,
                              void* d_out, int out_size, void* d_ws, size_t ws_size,
                              hipStream_t stream)
{
    const float* x         = (const float*)d_in[0];
    const float* enc_w1    = (const float*)d_in[1];
    const float* enc_b1    = (const float*)d_in[2];
    const float* enc_w2    = (const float*)d_in[3];
    const float* enc_b2    = (const float*)d_in[4];
    const float* enc_w3    = (const float*)d_in[5];
    const float* enc_b3    = (const float*)d_in[6];
    const float* enc_w4    = (const float*)d_in[7];
    const float* enc_b4    = (const float*)d_in[8];
    const float* enc_res_w1= (const float*)d_in[9];
    const float* enc_res_w2= (const float*)d_in[10];
    const float* enc_adj_w = (const float*)d_in[11];
    const float* enc_adj_b = (const float*)d_in[12];
    const float* Ecb       = (const float*)d_in[13];
    const float* dec_adj_w = (const float*)d_in[14];
    const float* dec_adj_b = (const float*)d_in[15];
    const float* dec_res_w1= (const float*)d_in[16];
    const float* dec_res_w2= (const float*)d_in[17];
    const float* tc1_w     = (const float*)d_in[18];
    const float* tc1_b     = (const float*)d_in[19];
    const float* tc2_w     = (const float*)d_in[20];
    const float* tc2_b     = (const float*)d_in[21];

    char* wsb = (char*)d_ws;
    u16*   wc2   = (u16*)(wsb + 0);
    u16*   wc3   = (u16*)(wsb + 262144);
    u16*   wc4   = (u16*)(wsb + 557056);
    u16*   wer1  = (u16*)(wsb + 851968);
    u16*   wer2  = (u16*)(wsb + 1146880);
    u16*   weadj = (u16*)(wsb + 1179648);
    u16*   wdadj = (u16*)(wsb + 1196032);
    u16*   wdr1  = (u16*)(wsb + 1343488);
    u16*   wdr2  = (u16*)(wsb + 1638400);
    u16*   wtc1  = (u16*)(wsb + 1671168);
    u16*   wtc2b = (u16*)(wsb + 1933312);
    float* counts= (float*)(wsb + 1951744);
    float* sse   = counts + 512;
    u16*   Ebf   = (u16*)(wsb + 1955840);
    float* enorm = (float*)(wsb + 2021376);
    u16*   H1    = (u16*)(wsb + 2097152);
    u16*   TR    = (u16*)(wsb + 35651584);
    u16*   H3    = (u16*)(wsb + 52428800);
    u16*   MID   = (u16*)(wsb + 69206016);
    u16*   ZE    = (u16*)(wsb + 77594624);
    u16*   ZQ    = (u16*)(wsb + 85983232);
    u16*   IDX   = (u16*)(wsb + 94371840);
    u16*   TC1O  = H1;

    float* out  = (float*)d_out;
    float* xrec = out + 1;
    float* tail = out + 1 + 3145728;

    Taps t3x3; t3x3.s = 1; t3x3.ntaps = 9;
    for (int kh = 0; kh < 3; ++kh) for (int kw = 0; kw < 3; ++kw) {
        t3x3.dh[kh*3+kw] = kh - 1; t3x3.dw[kh*3+kw] = kw - 1;
    }
    Taps t1x1; t1x1.s = 1; t1x1.ntaps = 1; t1x1.dh[0] = 0; t1x1.dw[0] = 0;
    Taps t4x4; t4x4.s = 2; t4x4.ntaps = 16;
    for (int kh = 0; kh < 4; ++kh) for (int kw = 0; kw < 4; ++kw) {
        t4x4.dh[kh*4+kw] = kh - 1; t4x4.dw[kh*4+kw] = kw - 1;
    }
    const int dtab[2][2] = {{0, -1}, {1, 0}};
    Taps ttc1[4];
    for (int p = 0; p < 4; ++p) {
        ttc1[p].s = 1; ttc1[p].ntaps = 4;
        for (int a = 0; a < 2; ++a) for (int bb = 0; bb < 2; ++bb) {
            ttc1[p].dh[a*2+bb] = dtab[p>>1][a];
            ttc1[p].dw[a*2+bb] = dtab[p&1][bb];
        }
    }

    // ---- weight transforms + sse zero ----
    zero_k<<<1, 256, 0, stream>>>(sse, 1);
    wconv_tf_k<<<512, 256, 0, stream>>>(enc_w2, wc2, 128, 64, 16, 131072);
    wconv_tf_k<<<576, 256, 0, stream>>>(enc_w3, wc3, 128, 128, 9, 147456);
    wconv_tf_k<<<576, 256, 0, stream>>>(enc_w4, wc4, 128, 128, 9, 147456);
    for (int i = 0; i < 2; ++i) {
        wconv_tf_k<<<288, 256, 0, stream>>>(enc_res_w1 + i*73728, wer1 + i*73728, 64, 128, 9, 73728);
        wconv_tf_k<<<32,  256, 0, stream>>>(enc_res_w2 + i*8192,  wer2 + i*8192,  128, 64, 1, 8192);
        wconv_tf_k<<<288, 256, 0, stream>>>(dec_res_w1 + i*73728, wdr1 + i*73728, 64, 128, 9, 73728);
        wconv_tf_k<<<32,  256, 0, stream>>>(dec_res_w2 + i*8192,  wdr2 + i*8192,  128, 64, 1, 8192);
    }
    wconv_tf_k<<<32,  256, 0, stream>>>(enc_adj_w, weadj, 64, 128, 1, 8192);
    wconv_tf_k<<<288, 256, 0, stream>>>(dec_adj_w, wdadj, 128, 64, 9, 73728);
    wtc1_tf_k<<<512, 256, 0, stream>>>(tc1_w, wtc1);
    wtc2b_tf_k<<<36, 256, 0, stream>>>(tc2_w, wtc2b);
    eprep_k<<<2, 256, 0, stream>>>(Ecb, Ebf, enorm);

    // ---- encoder ----
    conv1_k<<<1024, 256, 0, stream>>>(x, enc_w1, enc_b1, H1);
    mfma_conv_k<64,128,false,true,true,false><<<512, 256, 0, stream>>>
        (H1, wc2, enc_b2, TR, 64, 64, 32, 32, 1, 0, 0, t4x4);
    mfma_conv_k<128,128,false,true,true,false><<<512, 256, 0, stream>>>
        (TR, wc3, enc_b3, H3, 32, 32, 32, 32, 1, 0, 0, t3x3);
    mfma_conv_k<128,128,false,false,true,false><<<512, 256, 0, stream>>>
        (H3, wc4, enc_b4, TR, 32, 32, 32, 32, 1, 0, 0, t3x3);
    for (int i = 0; i < 2; ++i) {
        mfma_conv_k<128,64,true,false,false,false><<<512, 256, 0, stream>>>
            (TR, wer1 + i*73728, nullptr, MID, 32, 32, 32, 32, 1, 0, 0, t3x3);
        mfma_conv_k<64,128,true,false,false,true><<<512, 256, 0, stream>>>
            (MID, wer2 + i*8192, nullptr, TR, 32, 32, 32, 32, 1, 0, 0, t1x1);
    }
    mfma_conv_k<128,64,true,false,true,false><<<512, 256, 0, stream>>>
        (TR, weadj, enc_adj_b, ZE, 32, 32, 32, 32, 1, 0, 0, t1x1);

    // ---- VQ ----
    vq_mfma_k<<<1024, 256, 0, stream>>>(ZE, Ebf, enorm, ZQ, IDX, sse);
    hist_k<<<512, 256, 0, stream>>>(IDX, counts);

    // ---- decoder ----
    mfma_conv_k<64,128,false,false,true,false><<<512, 256, 0, stream>>>
        (ZQ, wdadj, dec_adj_b, H3, 32, 32, 32, 32, 1, 0, 0, t3x3);
    for (int i = 0; i < 2; ++i) {
        mfma_conv_k<128,64,true,false,false,false><<<512, 256, 0, stream>>>
            (H3, wdr1 + i*73728, nullptr, MID, 32, 32, 32, 32, 1, 0, 0, t3x3);
        mfma_conv_k<64,128,true,false,false,true><<<512, 256, 0, stream>>>
            (MID, wdr2 + i*8192, nullptr, H3, 32, 32, 32, 32, 1, 0, 0, t1x1);
    }
    for (int p = 0; p < 4; ++p) {
        mfma_conv_k<128,64,true,true,true,false><<<512, 256, 0, stream>>>
            (H3, wtc1 + p*32768, tc1_b, TC1O, 32, 32, 64, 64, 2, p>>1, p&1, ttc1[p]);
    }
    tc2_mfma_k<<<2048, 256, 0, stream>>>(TC1O, wtc2b, tc2_b, xrec);

    // ---- scalars ----
    finalize_k<<<1, 512, 0, stream>>>(counts, sse, out, tail);
}